// Round 8
// baseline (132318.896 us; speedup 1.0000x reference)
//
#include <hip/hip_runtime.h>
#include <hip/hip_bf16.h>

#define BTOT 16384

__device__ __forceinline__ float sig_(float x) {
    return __fdividef(1.0f, 1.0f + __expf(-x));
}
__device__ __forceinline__ float tanh_(float x) {
    float ax = fabsf(x);
    float e  = __expf(-2.0f * ax);
    float r  = __fdividef(1.0f - e, 1.0f + e);
    return x < 0.0f ? -r : r;
}

// ---------------------------------------------------------------------------
// Kernel 0: weight transpose. out[((u*K4+k4)*4+g)*4+j] = in[(g*U+u)*K + k4*4+j]
// ---------------------------------------------------------------------------
__global__ __launch_bounds__(256) void k_prep(
    const float* __restrict__ Win, float* __restrict__ Wout,
    int U, int K4, int n)
{
    const int e = blockIdx.x * 256 + threadIdx.x;
    if (e >= n) return;
    const int j  = e & 3;
    const int g  = (e >> 2) & 3;
    const int e4 = e >> 4;
    const int k4 = e4 % K4;
    const int u  = e4 / K4;
    const int K  = K4 * 4;
    Wout[e] = Win[(size_t)(g * U + u) * K + k4 * 4 + j];
}

// ---------------------------------------------------------------------------
// Kernel 1: the two (5 -> 100) LSTMs. grid = (512, 2), block = 512
// (32 rows x 16 ragged unit-groups: 4x7 + 12x6). 4 blocks/CU -> 32 waves/CU.
// LDS = 22,528 B. Output H{F,B} bf16 [t][u][b].
// ---------------------------------------------------------------------------
__global__ __launch_bounds__(512, 8) void k_lstm100(
    const float* __restrict__ x,
    const float* __restrict__ h0f, const float* __restrict__ c0f,
    const float* __restrict__ h0b, const float* __restrict__ c0b,
    const float* __restrict__ WihF, const float* __restrict__ bihF,
    const float* __restrict__ bhhF,
    const float* __restrict__ WihB, const float* __restrict__ bihB,
    const float* __restrict__ bhhB,
    const float* __restrict__ WhhTF, const float* __restrict__ WhhTB,
    __hip_bfloat16* __restrict__ HF, __hip_bfloat16* __restrict__ HB)
{
    const int dir = blockIdx.y;
    const float* h0   = dir ? h0b   : h0f;
    const float* c0   = dir ? c0b   : c0f;
    const float* Wih  = dir ? WihB  : WihF;
    const float* bih  = dir ? bihB  : bihF;
    const float* bhh  = dir ? bhhB  : bhhF;
    const float* WhhT = dir ? WhhTB : WhhTF;
    __hip_bfloat16* Hout = dir ? HB : HF;

    __shared__ float h_s[32][101];   // 12,928 B
    __shared__ float wih_s[2000];    //  8,000 B
    __shared__ float bias_s[400];    //  1,600 B

    const int tid  = threadIdx.x;
    const int r    = tid & 31;
    const int ug   = tid >> 5;                       // 0..15 (2 per wave)
    const int NU   = (ug < 4) ? 7 : 6;
    const int u0   = (ug < 4) ? ug * 7 : 28 + (ug - 4) * 6;
    const int rb   = blockIdx.x * 32;
    const int brow = rb + r;

    for (int i = tid; i < 2000; i += 512) wih_s[i] = Wih[i];
    for (int i = tid; i < 400;  i += 512) bias_s[i] = bih[i] + bhh[i];
    for (int i = tid; i < 3200; i += 512) h_s[i / 100][i % 100] = h0[(size_t)rb * 100 + i];

    float c[7];
    #pragma unroll
    for (int k = 0; k < 7; ++k)
        if (k < NU) c[k] = c0[(size_t)brow * 100 + u0 + k];
    __syncthreads();

    for (int t = 0; t < 20; ++t) {
        const int tt = dir ? (19 - t) : t;
        float xv[5];
        const float* xp = x + (size_t)tt * (BTOT * 5) + (size_t)brow * 5;
        #pragma unroll
        for (int i = 0; i < 5; ++i) xv[i] = xp[i];

        float acc[7][4];
        #pragma unroll
        for (int ju = 0; ju < 7; ++ju) {
            #pragma unroll
            for (int g = 0; g < 4; ++g) {
                if (ju < NU) {
                    const int row = g * 100 + u0 + ju;
                    float a = bias_s[row];
                    #pragma unroll
                    for (int i = 0; i < 5; ++i) a = fmaf(xv[i], wih_s[row * 5 + i], a);
                    acc[ju][g] = a;
                } else acc[ju][g] = 0.0f;
            }
        }

        const float* wbase = WhhT + u0 * 400;        // 25 k4 * 16 floats per unit
        #pragma unroll 1
        for (int i4 = 0; i4 < 25; ++i4) {
            const float hv0 = h_s[r][i4 * 4 + 0];
            const float hv1 = h_s[r][i4 * 4 + 1];
            const float hv2 = h_s[r][i4 * 4 + 2];
            const float hv3 = h_s[r][i4 * 4 + 3];
            #pragma unroll
            for (int ju = 0; ju < 7; ++ju) {
                if (ju < NU) {
                    const float* wp = wbase + ju * 400 + i4 * 16;
                    #pragma unroll
                    for (int g = 0; g < 4; ++g) {
                        const float4 w = *reinterpret_cast<const float4*>(wp + g * 4);
                        float a = acc[ju][g];
                        a = fmaf(hv0, w.x, a); a = fmaf(hv1, w.y, a);
                        a = fmaf(hv2, w.z, a); a = fmaf(hv3, w.w, a);
                        acc[ju][g] = a;
                    }
                }
            }
        }

        float hnew[7];
        #pragma unroll
        for (int ju = 0; ju < 7; ++ju) {
            if (ju < NU) {
                const float ig = sig_(acc[ju][0]);
                const float fg = sig_(acc[ju][1]);
                const float gg = tanh_(acc[ju][2]);
                const float og = sig_(acc[ju][3]);
                const float cn = fmaf(fg, c[ju], ig * gg);
                c[ju] = cn;
                hnew[ju] = og * tanh_(cn);
            }
        }
        __syncthreads();
        #pragma unroll
        for (int k = 0; k < 7; ++k) {
            if (k < NU) {
                h_s[r][u0 + k] = hnew[k];
                Hout[((size_t)tt * 100 + u0 + k) * BTOT + brow] = __float2bfloat16(hnew[k]);
            }
        }
        __syncthreads();
    }
}

// ---------------------------------------------------------------------------
// Kernel 2: middle (200 -> 200) LSTM. grid = 1024, block = 512
// (16 rows x 32 ragged unit-groups: 8x7 + 24x6). 4 blocks/CU -> 32 waves/CU.
// LDS = 16,128 B. Final h -> HM bf16 [b][u].
// ---------------------------------------------------------------------------
__global__ __launch_bounds__(512, 8) void k_mid(
    const float* __restrict__ h0m, const float* __restrict__ c0m,
    const float* __restrict__ bih, const float* __restrict__ bhh,
    const float* __restrict__ WihT, const float* __restrict__ WhhT,
    const __hip_bfloat16* __restrict__ HF, const __hip_bfloat16* __restrict__ HB,
    __hip_bfloat16* __restrict__ HM)
{
    __shared__ float bufA[16][101];   // 6,464 B
    __shared__ float bufB[16][101];   // 6,464 B
    __shared__ float bias_s[800];     // 3,200 B

    const int tid  = threadIdx.x;
    const int r    = tid & 15;
    const int ug   = tid >> 4;                       // 0..31 (4 per wave)
    const int NU   = (ug < 8) ? 7 : 6;
    const int u0   = (ug < 8) ? ug * 7 : 56 + (ug - 8) * 6;
    const int rb   = blockIdx.x * 16;
    const int brow = rb + r;

    for (int i = tid; i < 800; i += 512) bias_s[i] = bih[i] + bhh[i];

    float hm[7], cm[7];
    #pragma unroll
    for (int k = 0; k < 7; ++k) {
        if (k < NU) {
            hm[k] = h0m[(size_t)brow * 200 + u0 + k];
            cm[k] = c0m[(size_t)brow * 200 + u0 + k];
        }
    }
    __syncthreads();

    for (int t = 0; t < 20; ++t) {
        // ---- S1: stage hf[t] -> bufA, hb[t] -> bufB ----
        const __hip_bfloat16* HFt = HF + (size_t)t * 100 * BTOT + rb;
        const __hip_bfloat16* HBt = HB + (size_t)t * 100 * BTOT + rb;
        for (int i = tid; i < 1600; i += 512) {
            const int rr = i & 15;
            const int u  = i >> 4;
            bufA[rr][u] = __bfloat162float(HFt[(size_t)u * BTOT + rr]);
            bufB[rr][u] = __bfloat162float(HBt[(size_t)u * BTOT + rr]);
        }
        __syncthreads();

        // ---- S2: acc = bias + WihT * [hf|hb] ----
        float acc[7][4];
        #pragma unroll
        for (int ju = 0; ju < 7; ++ju)
            #pragma unroll
            for (int g = 0; g < 4; ++g)
                acc[ju][g] = (ju < NU) ? bias_s[g * 200 + u0 + ju] : 0.0f;

        const float* wbi = WihT + u0 * 800;          // 50 k4 * 16 floats per unit
        #pragma unroll 1
        for (int i4 = 0; i4 < 25; ++i4) {            // hf half (k4 = i4)
            const float a0 = bufA[r][i4 * 4 + 0];
            const float a1 = bufA[r][i4 * 4 + 1];
            const float a2 = bufA[r][i4 * 4 + 2];
            const float a3 = bufA[r][i4 * 4 + 3];
            #pragma unroll
            for (int ju = 0; ju < 7; ++ju) {
                if (ju < NU) {
                    const float* wp = wbi + ju * 800 + i4 * 16;
                    #pragma unroll
                    for (int g = 0; g < 4; ++g) {
                        const float4 w = *reinterpret_cast<const float4*>(wp + g * 4);
                        float a = acc[ju][g];
                        a = fmaf(a0, w.x, a); a = fmaf(a1, w.y, a);
                        a = fmaf(a2, w.z, a); a = fmaf(a3, w.w, a);
                        acc[ju][g] = a;
                    }
                }
            }
        }
        #pragma unroll 1
        for (int i4 = 0; i4 < 25; ++i4) {            // hb half (k4 = 25+i4)
            const float b0 = bufB[r][i4 * 4 + 0];
            const float b1 = bufB[r][i4 * 4 + 1];
            const float b2 = bufB[r][i4 * 4 + 2];
            const float b3 = bufB[r][i4 * 4 + 3];
            #pragma unroll
            for (int ju = 0; ju < 7; ++ju) {
                if (ju < NU) {
                    const float* wp = wbi + ju * 800 + (25 + i4) * 16;
                    #pragma unroll
                    for (int g = 0; g < 4; ++g) {
                        const float4 w = *reinterpret_cast<const float4*>(wp + g * 4);
                        float a = acc[ju][g];
                        a = fmaf(b0, w.x, a); a = fmaf(b1, w.y, a);
                        a = fmaf(b2, w.z, a); a = fmaf(b3, w.w, a);
                        acc[ju][g] = a;
                    }
                }
            }
        }
        __syncthreads();

        // ---- S3: publish hm[t-1]: units 0..99 -> bufA, 100..199 -> bufB ----
        #pragma unroll
        for (int k = 0; k < 7; ++k) {
            if (k < NU) {
                const int u = u0 + k;
                if (u < 100) bufA[r][u] = hm[k];
                else         bufB[r][u - 100] = hm[k];
            }
        }
        __syncthreads();

        // ---- S4: acc += WhhT * hm; gates ----
        const float* wbh = WhhT + u0 * 800;
        #pragma unroll 1
        for (int i4 = 0; i4 < 25; ++i4) {
            const float a0 = bufA[r][i4 * 4 + 0];
            const float a1 = bufA[r][i4 * 4 + 1];
            const float a2 = bufA[r][i4 * 4 + 2];
            const float a3 = bufA[r][i4 * 4 + 3];
            #pragma unroll
            for (int ju = 0; ju < 7; ++ju) {
                if (ju < NU) {
                    const float* wp = wbh + ju * 800 + i4 * 16;
                    #pragma unroll
                    for (int g = 0; g < 4; ++g) {
                        const float4 w = *reinterpret_cast<const float4*>(wp + g * 4);
                        float a = acc[ju][g];
                        a = fmaf(a0, w.x, a); a = fmaf(a1, w.y, a);
                        a = fmaf(a2, w.z, a); a = fmaf(a3, w.w, a);
                        acc[ju][g] = a;
                    }
                }
            }
        }
        #pragma unroll 1
        for (int i4 = 0; i4 < 25; ++i4) {
            const float b0 = bufB[r][i4 * 4 + 0];
            const float b1 = bufB[r][i4 * 4 + 1];
            const float b2 = bufB[r][i4 * 4 + 2];
            const float b3 = bufB[r][i4 * 4 + 3];
            #pragma unroll
            for (int ju = 0; ju < 7; ++ju) {
                if (ju < NU) {
                    const float* wp = wbh + ju * 800 + (25 + i4) * 16;
                    #pragma unroll
                    for (int g = 0; g < 4; ++g) {
                        const float4 w = *reinterpret_cast<const float4*>(wp + g * 4);
                        float a = acc[ju][g];
                        a = fmaf(b0, w.x, a); a = fmaf(b1, w.y, a);
                        a = fmaf(b2, w.z, a); a = fmaf(b3, w.w, a);
                        acc[ju][g] = a;
                    }
                }
            }
        }
        #pragma unroll
        for (int ju = 0; ju < 7; ++ju) {
            if (ju < NU) {
                const float ig = sig_(acc[ju][0]);
                const float fg = sig_(acc[ju][1]);
                const float gg = tanh_(acc[ju][2]);
                const float og = sig_(acc[ju][3]);
                const float cn = fmaf(fg, cm[ju], ig * gg);
                cm[ju] = cn;
                hm[ju] = og * tanh_(cn);
            }
        }
        __syncthreads();
    }

    #pragma unroll
    for (int k = 0; k < 7; ++k)
        if (k < NU)
            HM[(size_t)brow * 200 + u0 + k] = __float2bfloat16(hm[k]);
}

// ---------------------------------------------------------------------------
// Kernel 3: dense + convT chain with zero-padded LDS tiles.
// Unified tap identity (stride2, pad1, k4): with padded x_p (x_p[i+1]=x[i],
// zeros at both ends): out[l] = sum_ci x_p[q+1]*wHI + x_p[q]*wLO,
// q=(l+1)>>1; even l: (wHI,wLO)=(w[1],w[3]); odd l: (w[0],w[2]).
// conv2 threads: 64 co x 4 even l-segments of 28. LDS = 60,308 B.
// ---------------------------------------------------------------------------
__global__ __launch_bounds__(256, 2) void k_head(
    const __hip_bfloat16* __restrict__ HM,
    const float* __restrict__ Wd, const float* __restrict__ bd,
    const float* __restrict__ w1, const float* __restrict__ b1,
    const float* __restrict__ w2, const float* __restrict__ b2,
    const float* __restrict__ w3, const float* __restrict__ b3,
    const float* __restrict__ g1, const float* __restrict__ be1,
    const float* __restrict__ m1, const float* __restrict__ v1,
    const float* __restrict__ g2, const float* __restrict__ be2,
    const float* __restrict__ m2, const float* __restrict__ v2,
    float* __restrict__ out)
{
    __shared__ float hm_s[200];
    __shared__ float y27p[29];        // data 1..27, zeros at 0, 28
    __shared__ float t1p[128][58];    // data 1..54, zeros at 0, 55, 56, 57
    __shared__ float t2p[64][110];    // data 1..108, zeros at 0, 109
    __shared__ float sc1[128], sh1[128], sc2[64], sh2[64];

    const int tid = threadIdx.x;
    const int b   = blockIdx.x;

    if (tid < 200) hm_s[tid] = __bfloat162float(HM[(size_t)b * 200 + tid]);
    if (tid < 128) {
        const float s = g1[tid] * __frsqrt_rn(v1[tid] + 1e-5f);
        sc1[tid] = s; sh1[tid] = be1[tid] - m1[tid] * s;
    } else if (tid < 192) {
        const int cc = tid - 128;
        const float s = g2[cc] * __frsqrt_rn(v2[cc] + 1e-5f);
        sc2[cc] = s; sh2[cc] = be2[cc] - m2[cc] * s;
    }
    {   // zero pads
        const int co = tid >> 1;
        t1p[co][(tid & 1) ? 55 : 0] = 0.0f;
        if (tid < 128) { t1p[tid][56] = 0.0f; t1p[tid][57] = 0.0f; }
        if (tid < 64)  { t2p[tid][0] = 0.0f; t2p[tid][109] = 0.0f; }
        if (tid == 0)  { y27p[0] = 0.0f; y27p[28] = 0.0f; }
    }
    __syncthreads();

    if (tid < 27) {                                   // dense 200 -> 27
        float a = bd[tid];
        const float* wr = Wd + tid * 200;
        for (int i = 0; i < 200; ++i) a = fmaf(hm_s[i], wr[i], a);
        y27p[tid + 1] = a;
    }
    __syncthreads();

    // conv1 (1 -> 128, 27 -> 54) + bn1 + relu -> t1p
    for (int idx = tid; idx < 128 * 54; idx += 256) {
        const int co = idx / 54;
        const int l  = idx - co * 54;
        const int q  = (l + 1) >> 1;
        const float4 w = *reinterpret_cast<const float4*>(w1 + co * 4);
        const float wHI = (l & 1) ? w.x : w.y;
        const float wLO = (l & 1) ? w.z : w.w;
        float a = b1[co];
        a = fmaf(y27p[q + 1], wHI, a);
        a = fmaf(y27p[q],     wLO, a);
        a = fmaf(a, sc1[co], sh1[co]);
        t1p[co][l + 1] = fmaxf(a, 0.0f);
    }
    __syncthreads();

    // conv2 (128 -> 64, 54 -> 108) + bn2 + relu -> t2p
    {
        const int co   = tid & 63;
        const int lseg = tid >> 6;        // 0..3 (uniform per wave)
        const int l0   = lseg * 28;       // even
        const int qb   = lseg * 14;
        float acc[28];
        const float bb = b2[co];
        #pragma unroll
        for (int j = 0; j < 28; ++j) acc[j] = bb;

        #pragma unroll 2
        for (int ci = 0; ci < 128; ++ci) {
            float tv[16];
            #pragma unroll
            for (int j = 0; j < 16; ++j) tv[j] = t1p[ci][qb + j];
            const float4 w = *reinterpret_cast<const float4*>(
                w2 + ((size_t)((ci << 6) + co) << 2));
            #pragma unroll
            for (int j = 0; j < 28; ++j) {
                const int qi = (j + 1) >> 1;               // compile-time
                const float wHI = (j & 1) ? w.x : w.y;
                const float wLO = (j & 1) ? w.z : w.w;
                acc[j] = fmaf(tv[qi + 1], wHI, acc[j]);
                acc[j] = fmaf(tv[qi],     wLO, acc[j]);
            }
        }
        const float s2 = sc2[co], h2 = sh2[co];
        #pragma unroll
        for (int j = 0; j < 28; ++j) {
            const int l = l0 + j;
            if (l < 108) t2p[co][l + 1] = fmaxf(fmaf(acc[j], s2, h2), 0.0f);
        }
    }
    __syncthreads();

    // conv3 (64 -> 1, 108 -> 216)
    if (tid < 216) {
        const int l = tid;
        const int q = (l + 1) >> 1;
        const bool odd = (l & 1) != 0;
        float a = b3[0];
        #pragma unroll 4
        for (int ci = 0; ci < 64; ++ci) {
            const float4 w = *reinterpret_cast<const float4*>(w3 + ci * 4);
            const float wHI = odd ? w.x : w.y;
            const float wLO = odd ? w.z : w.w;
            a = fmaf(t2p[ci][q + 1], wHI, a);
            a = fmaf(t2p[ci][q],     wLO, a);
        }
        out[(size_t)b * 216 + l] = a;
    }
}

// ---------------------------------------------------------------------------
extern "C" void kernel_launch(void* const* d_in, const int* in_sizes, int n_in,
                              void* d_out, int out_size, void* d_ws, size_t ws_size,
                              hipStream_t stream) {
    const float* x     = (const float*)d_in[0];
    const float* h0f   = (const float*)d_in[1];
    const float* c0f   = (const float*)d_in[2];
    const float* h0b   = (const float*)d_in[3];
    const float* c0b   = (const float*)d_in[4];
    const float* h0m   = (const float*)d_in[5];
    const float* c0m   = (const float*)d_in[6];
    const float* Wih_f = (const float*)d_in[7];
    const float* Whh_f = (const float*)d_in[8];
    const float* bih_f = (const float*)d_in[9];
    const float* bhh_f = (const float*)d_in[10];
    const float* Wih_b = (const float*)d_in[11];
    const float* Whh_b = (const float*)d_in[12];
    const float* bih_b = (const float*)d_in[13];
    const float* bhh_b = (const float*)d_in[14];
    const float* Wih_m = (const float*)d_in[15];
    const float* Whh_m = (const float*)d_in[16];
    const float* bih_m = (const float*)d_in[17];
    const float* bhh_m = (const float*)d_in[18];
    const float* Wd    = (const float*)d_in[19];
    const float* bd    = (const float*)d_in[20];
    const float* w1    = (const float*)d_in[21];
    const float* b1    = (const float*)d_in[22];
    const float* w2    = (const float*)d_in[23];
    const float* b2    = (const float*)d_in[24];
    const float* w3    = (const float*)d_in[25];
    const float* b3    = (const float*)d_in[26];
    const float* g1    = (const float*)d_in[27];
    const float* be1   = (const float*)d_in[28];
    const float* m1    = (const float*)d_in[29];
    const float* v1    = (const float*)d_in[30];
    const float* g2    = (const float*)d_in[31];
    const float* be2   = (const float*)d_in[32];
    const float* m2    = (const float*)d_in[33];
    const float* v2    = (const float*)d_in[34];

    // ws layout (bytes), total 139,225,600 (proven <= ws_size in round 6/7):
    char* ws = (char*)d_ws;
    __hip_bfloat16* HF = (__hip_bfloat16*)ws;
    __hip_bfloat16* HB = (__hip_bfloat16*)(ws + 65536000);
    float* WihT_m = (float*)(ws + 131072000);
    float* WhhT_m = (float*)(ws + 131712000);
    float* WhhT_f = (float*)(ws + 132352000);
    float* WhhT_b = (float*)(ws + 132512000);
    __hip_bfloat16* HM = (__hip_bfloat16*)(ws + 132672000);

    k_prep<<<(160000 + 255) / 256, 256, 0, stream>>>(Wih_m, WihT_m, 200, 50, 160000);
    k_prep<<<(160000 + 255) / 256, 256, 0, stream>>>(Whh_m, WhhT_m, 200, 50, 160000);
    k_prep<<<(40000  + 255) / 256, 256, 0, stream>>>(Whh_f, WhhT_f, 100, 25, 40000);
    k_prep<<<(40000  + 255) / 256, 256, 0, stream>>>(Whh_b, WhhT_b, 100, 25, 40000);

    k_lstm100<<<dim3(512, 2), 512, 0, stream>>>(
        x, h0f, c0f, h0b, c0b,
        Wih_f, bih_f, bhh_f,
        Wih_b, bih_b, bhh_b,
        WhhT_f, WhhT_b, HF, HB);

    k_mid<<<1024, 512, 0, stream>>>(
        h0m, c0m, bih_m, bhh_m, WihT_m, WhhT_m, HF, HB, HM);

    k_head<<<16384, 256, 0, stream>>>(
        HM, Wd, bd, w1, b1, w2, b2, w3, b3,
        g1, be1, m1, v1, g2, be2, m2, v2, (float*)d_out);
}

// Round 9
// 32370.923 us; speedup vs baseline: 4.0876x; 4.0876x over previous
//
#include <hip/hip_runtime.h>
#include <hip/hip_bf16.h>

#define BTOT 16384

__device__ __forceinline__ float sig_(float x) {
    return __fdividef(1.0f, 1.0f + __expf(-x));
}
__device__ __forceinline__ float tanh_(float x) {
    float ax = fabsf(x);
    float e  = __expf(-2.0f * ax);
    float r  = __fdividef(1.0f - e, 1.0f + e);
    return x < 0.0f ? -r : r;
}

// ---------------------------------------------------------------------------
// Kernel 0: weight transpose. out[((u*K4+k4)*4+g)*4+j] = in[(g*U+u)*K + k4*4+j]
// ---------------------------------------------------------------------------
__global__ __launch_bounds__(256) void k_prep(
    const float* __restrict__ Win, float* __restrict__ Wout,
    int U, int K4, int n)
{
    const int e = blockIdx.x * 256 + threadIdx.x;
    if (e >= n) return;
    const int j  = e & 3;
    const int g  = (e >> 2) & 3;
    const int e4 = e >> 4;
    const int k4 = e4 % K4;
    const int u  = e4 / K4;
    const int K  = K4 * 4;
    Wout[e] = Win[(size_t)(g * U + u) * K + k4 * 4 + j];
}

// ---------------------------------------------------------------------------
// Kernel 1 (round-7 PROVEN): the two (5 -> 100) LSTMs. grid = (256, 2),
// block = 512, 8 ragged unit-groups (4x13 + 4x12) x 64 rows, lb(512,4).
// LDS = 35,456 B. Output H{F,B} bf16 [t][u][b].
// ---------------------------------------------------------------------------
__global__ __launch_bounds__(512, 4) void k_lstm100(
    const float* __restrict__ x,
    const float* __restrict__ h0f, const float* __restrict__ c0f,
    const float* __restrict__ h0b, const float* __restrict__ c0b,
    const float* __restrict__ WihF, const float* __restrict__ bihF,
    const float* __restrict__ bhhF,
    const float* __restrict__ WihB, const float* __restrict__ bihB,
    const float* __restrict__ bhhB,
    const float* __restrict__ WhhTF, const float* __restrict__ WhhTB,
    __hip_bfloat16* __restrict__ HF, __hip_bfloat16* __restrict__ HB)
{
    const int dir = blockIdx.y;
    const float* h0   = dir ? h0b   : h0f;
    const float* c0   = dir ? c0b   : c0f;
    const float* Wih  = dir ? WihB  : WihF;
    const float* bih  = dir ? bihB  : bihF;
    const float* bhh  = dir ? bhhB  : bhhF;
    const float* WhhT = dir ? WhhTB : WhhTF;
    __hip_bfloat16* Hout = dir ? HB : HF;

    __shared__ float h_s[64][101];
    __shared__ float wih_s[2000];
    __shared__ float bias_s[400];

    const int tid  = threadIdx.x;
    const int r    = tid & 63;
    const int ug   = __builtin_amdgcn_readfirstlane(tid >> 6);  // 0..7
    const int NU   = (ug < 4) ? 13 : 12;
    const int u0   = (ug < 4) ? ug * 13 : 52 + (ug - 4) * 12;
    const int rb   = blockIdx.x * 64;
    const int brow = rb + r;

    for (int i = tid; i < 2000; i += 512) wih_s[i] = Wih[i];
    for (int i = tid; i < 400;  i += 512) bias_s[i] = bih[i] + bhh[i];
    for (int i = tid; i < 6400; i += 512) h_s[i / 100][i % 100] = h0[(size_t)rb * 100 + i];

    float c[13];
    #pragma unroll
    for (int k = 0; k < 13; ++k)
        if (k < NU) c[k] = c0[(size_t)brow * 100 + u0 + k];
    __syncthreads();

    for (int t = 0; t < 20; ++t) {
        const int tt = dir ? (19 - t) : t;
        float xv[5];
        const float* xp = x + (size_t)tt * (BTOT * 5) + (size_t)brow * 5;
        #pragma unroll
        for (int i = 0; i < 5; ++i) xv[i] = xp[i];

        float acc[13][4];
        #pragma unroll
        for (int ju = 0; ju < 13; ++ju) {
            if (ju < NU) {
                #pragma unroll
                for (int g = 0; g < 4; ++g) {
                    const int row = g * 100 + u0 + ju;
                    float a = bias_s[row];
                    #pragma unroll
                    for (int i = 0; i < 5; ++i) a = fmaf(xv[i], wih_s[row * 5 + i], a);
                    acc[ju][g] = a;
                }
            }
        }

        #pragma unroll 1
        for (int i4 = 0; i4 < 25; ++i4) {
            const float hv0 = h_s[r][i4 * 4 + 0];
            const float hv1 = h_s[r][i4 * 4 + 1];
            const float hv2 = h_s[r][i4 * 4 + 2];
            const float hv3 = h_s[r][i4 * 4 + 3];
            #pragma unroll
            for (int ju = 0; ju < 13; ++ju) {
                if (ju < NU) {
                    const float* wp = WhhT + (((size_t)(u0 + ju) * 25 + i4) << 4);
                    #pragma unroll
                    for (int g = 0; g < 4; ++g) {
                        const float4 w = *reinterpret_cast<const float4*>(wp + g * 4);
                        float a = acc[ju][g];
                        a = fmaf(hv0, w.x, a); a = fmaf(hv1, w.y, a);
                        a = fmaf(hv2, w.z, a); a = fmaf(hv3, w.w, a);
                        acc[ju][g] = a;
                    }
                }
            }
        }

        float hnew[13];
        #pragma unroll
        for (int ju = 0; ju < 13; ++ju) {
            if (ju < NU) {
                const float ig = sig_(acc[ju][0]);
                const float fg = sig_(acc[ju][1]);
                const float gg = tanh_(acc[ju][2]);
                const float og = sig_(acc[ju][3]);
                const float cn = fmaf(fg, c[ju], ig * gg);
                c[ju] = cn;
                hnew[ju] = og * tanh_(cn);
            }
        }
        __syncthreads();
        #pragma unroll
        for (int k = 0; k < 13; ++k) {
            if (k < NU) {
                h_s[r][u0 + k] = hnew[k];
                Hout[((size_t)tt * 100 + u0 + k) * BTOT + brow] = __float2bfloat16(hnew[k]);
            }
        }
        __syncthreads();
    }
}

// ---------------------------------------------------------------------------
// Kernel 2: middle (200 -> 200) LSTM. grid = 1024, block = 512
// (16 rows x 32 ragged unit-groups: 8x7 + 24x6). lb(512,4): VGPR cap 128,
// NO spill (round-8 lesson: lb(512,8) forced 32 VGPR -> 538 GB scratch).
// LDS = 16,128 B. Final h -> HM bf16 [b][u].
// ---------------------------------------------------------------------------
__global__ __launch_bounds__(512, 4) void k_mid(
    const float* __restrict__ h0m, const float* __restrict__ c0m,
    const float* __restrict__ bih, const float* __restrict__ bhh,
    const float* __restrict__ WihT, const float* __restrict__ WhhT,
    const __hip_bfloat16* __restrict__ HF, const __hip_bfloat16* __restrict__ HB,
    __hip_bfloat16* __restrict__ HM)
{
    __shared__ float bufA[16][101];
    __shared__ float bufB[16][101];
    __shared__ float bias_s[800];

    const int tid  = threadIdx.x;
    const int r    = tid & 15;
    const int ug   = tid >> 4;                       // 0..31 (4 per wave)
    const int NU   = (ug < 8) ? 7 : 6;
    const int u0   = (ug < 8) ? ug * 7 : 56 + (ug - 8) * 6;
    const int rb   = blockIdx.x * 16;
    const int brow = rb + r;

    for (int i = tid; i < 800; i += 512) bias_s[i] = bih[i] + bhh[i];

    float hm[7], cm[7];
    #pragma unroll
    for (int k = 0; k < 7; ++k) {
        if (k < NU) {
            hm[k] = h0m[(size_t)brow * 200 + u0 + k];
            cm[k] = c0m[(size_t)brow * 200 + u0 + k];
        }
    }
    __syncthreads();

    for (int t = 0; t < 20; ++t) {
        // ---- S1: stage hf[t] -> bufA, hb[t] -> bufB ----
        const __hip_bfloat16* HFt = HF + (size_t)t * 100 * BTOT + rb;
        const __hip_bfloat16* HBt = HB + (size_t)t * 100 * BTOT + rb;
        for (int i = tid; i < 1600; i += 512) {
            const int rr = i & 15;
            const int u  = i >> 4;
            bufA[rr][u] = __bfloat162float(HFt[(size_t)u * BTOT + rr]);
            bufB[rr][u] = __bfloat162float(HBt[(size_t)u * BTOT + rr]);
        }
        __syncthreads();

        // ---- S2: acc = bias + WihT * [hf|hb] ----
        float acc[7][4];
        #pragma unroll
        for (int ju = 0; ju < 7; ++ju)
            #pragma unroll
            for (int g = 0; g < 4; ++g)
                acc[ju][g] = (ju < NU) ? bias_s[g * 200 + u0 + ju] : 0.0f;

        const float* wbi = WihT + u0 * 800;
        #pragma unroll 1
        for (int i4 = 0; i4 < 25; ++i4) {            // hf half
            const float a0 = bufA[r][i4 * 4 + 0];
            const float a1 = bufA[r][i4 * 4 + 1];
            const float a2 = bufA[r][i4 * 4 + 2];
            const float a3 = bufA[r][i4 * 4 + 3];
            #pragma unroll
            for (int ju = 0; ju < 7; ++ju) {
                if (ju < NU) {
                    const float* wp = wbi + ju * 800 + i4 * 16;
                    #pragma unroll
                    for (int g = 0; g < 4; ++g) {
                        const float4 w = *reinterpret_cast<const float4*>(wp + g * 4);
                        float a = acc[ju][g];
                        a = fmaf(a0, w.x, a); a = fmaf(a1, w.y, a);
                        a = fmaf(a2, w.z, a); a = fmaf(a3, w.w, a);
                        acc[ju][g] = a;
                    }
                }
            }
        }
        #pragma unroll 1
        for (int i4 = 0; i4 < 25; ++i4) {            // hb half
            const float b0 = bufB[r][i4 * 4 + 0];
            const float b1 = bufB[r][i4 * 4 + 1];
            const float b2 = bufB[r][i4 * 4 + 2];
            const float b3 = bufB[r][i4 * 4 + 3];
            #pragma unroll
            for (int ju = 0; ju < 7; ++ju) {
                if (ju < NU) {
                    const float* wp = wbi + ju * 800 + (25 + i4) * 16;
                    #pragma unroll
                    for (int g = 0; g < 4; ++g) {
                        const float4 w = *reinterpret_cast<const float4*>(wp + g * 4);
                        float a = acc[ju][g];
                        a = fmaf(b0, w.x, a); a = fmaf(b1, w.y, a);
                        a = fmaf(b2, w.z, a); a = fmaf(b3, w.w, a);
                        acc[ju][g] = a;
                    }
                }
            }
        }
        __syncthreads();

        // ---- S3: publish hm[t-1]: units 0..99 -> bufA, 100..199 -> bufB ----
        #pragma unroll
        for (int k = 0; k < 7; ++k) {
            if (k < NU) {
                const int u = u0 + k;
                if (u < 100) bufA[r][u] = hm[k];
                else         bufB[r][u - 100] = hm[k];
            }
        }
        __syncthreads();

        // ---- S4: acc += WhhT * hm; gates ----
        const float* wbh = WhhT + u0 * 800;
        #pragma unroll 1
        for (int i4 = 0; i4 < 25; ++i4) {
            const float a0 = bufA[r][i4 * 4 + 0];
            const float a1 = bufA[r][i4 * 4 + 1];
            const float a2 = bufA[r][i4 * 4 + 2];
            const float a3 = bufA[r][i4 * 4 + 3];
            #pragma unroll
            for (int ju = 0; ju < 7; ++ju) {
                if (ju < NU) {
                    const float* wp = wbh + ju * 800 + i4 * 16;
                    #pragma unroll
                    for (int g = 0; g < 4; ++g) {
                        const float4 w = *reinterpret_cast<const float4*>(wp + g * 4);
                        float a = acc[ju][g];
                        a = fmaf(a0, w.x, a); a = fmaf(a1, w.y, a);
                        a = fmaf(a2, w.z, a); a = fmaf(a3, w.w, a);
                        acc[ju][g] = a;
                    }
                }
            }
        }
        #pragma unroll 1
        for (int i4 = 0; i4 < 25; ++i4) {
            const float b0 = bufB[r][i4 * 4 + 0];
            const float b1 = bufB[r][i4 * 4 + 1];
            const float b2 = bufB[r][i4 * 4 + 2];
            const float b3 = bufB[r][i4 * 4 + 3];
            #pragma unroll
            for (int ju = 0; ju < 7; ++ju) {
                if (ju < NU) {
                    const float* wp = wbh + ju * 800 + (25 + i4) * 16;
                    #pragma unroll
                    for (int g = 0; g < 4; ++g) {
                        const float4 w = *reinterpret_cast<const float4*>(wp + g * 4);
                        float a = acc[ju][g];
                        a = fmaf(b0, w.x, a); a = fmaf(b1, w.y, a);
                        a = fmaf(b2, w.z, a); a = fmaf(b3, w.w, a);
                        acc[ju][g] = a;
                    }
                }
            }
        }
        #pragma unroll
        for (int ju = 0; ju < 7; ++ju) {
            if (ju < NU) {
                const float ig = sig_(acc[ju][0]);
                const float fg = sig_(acc[ju][1]);
                const float gg = tanh_(acc[ju][2]);
                const float og = sig_(acc[ju][3]);
                const float cn = fmaf(fg, cm[ju], ig * gg);
                cm[ju] = cn;
                hm[ju] = og * tanh_(cn);
            }
        }
        __syncthreads();
    }

    #pragma unroll
    for (int k = 0; k < 7; ++k)
        if (k < NU)
            HM[(size_t)brow * 200 + u0 + k] = __float2bfloat16(hm[k]);
}

// ---------------------------------------------------------------------------
// Kernel 3: dense + convT chain, zero-padded LDS tiles (round-8, proven).
// ---------------------------------------------------------------------------
__global__ __launch_bounds__(256, 2) void k_head(
    const __hip_bfloat16* __restrict__ HM,
    const float* __restrict__ Wd, const float* __restrict__ bd,
    const float* __restrict__ w1, const float* __restrict__ b1,
    const float* __restrict__ w2, const float* __restrict__ b2,
    const float* __restrict__ w3, const float* __restrict__ b3,
    const float* __restrict__ g1, const float* __restrict__ be1,
    const float* __restrict__ m1, const float* __restrict__ v1,
    const float* __restrict__ g2, const float* __restrict__ be2,
    const float* __restrict__ m2, const float* __restrict__ v2,
    float* __restrict__ out)
{
    __shared__ float hm_s[200];
    __shared__ float y27p[29];
    __shared__ float t1p[128][58];
    __shared__ float t2p[64][110];
    __shared__ float sc1[128], sh1[128], sc2[64], sh2[64];

    const int tid = threadIdx.x;
    const int b   = blockIdx.x;

    if (tid < 200) hm_s[tid] = __bfloat162float(HM[(size_t)b * 200 + tid]);
    if (tid < 128) {
        const float s = g1[tid] * __frsqrt_rn(v1[tid] + 1e-5f);
        sc1[tid] = s; sh1[tid] = be1[tid] - m1[tid] * s;
    } else if (tid < 192) {
        const int cc = tid - 128;
        const float s = g2[cc] * __frsqrt_rn(v2[cc] + 1e-5f);
        sc2[cc] = s; sh2[cc] = be2[cc] - m2[cc] * s;
    }
    {
        const int co = tid >> 1;
        t1p[co][(tid & 1) ? 55 : 0] = 0.0f;
        if (tid < 128) { t1p[tid][56] = 0.0f; t1p[tid][57] = 0.0f; }
        if (tid < 64)  { t2p[tid][0] = 0.0f; t2p[tid][109] = 0.0f; }
        if (tid == 0)  { y27p[0] = 0.0f; y27p[28] = 0.0f; }
    }
    __syncthreads();

    if (tid < 27) {
        float a = bd[tid];
        const float* wr = Wd + tid * 200;
        for (int i = 0; i < 200; ++i) a = fmaf(hm_s[i], wr[i], a);
        y27p[tid + 1] = a;
    }
    __syncthreads();

    for (int idx = tid; idx < 128 * 54; idx += 256) {
        const int co = idx / 54;
        const int l  = idx - co * 54;
        const int q  = (l + 1) >> 1;
        const float4 w = *reinterpret_cast<const float4*>(w1 + co * 4);
        const float wHI = (l & 1) ? w.x : w.y;
        const float wLO = (l & 1) ? w.z : w.w;
        float a = b1[co];
        a = fmaf(y27p[q + 1], wHI, a);
        a = fmaf(y27p[q],     wLO, a);
        a = fmaf(a, sc1[co], sh1[co]);
        t1p[co][l + 1] = fmaxf(a, 0.0f);
    }
    __syncthreads();

    {
        const int co   = tid & 63;
        const int lseg = tid >> 6;
        const int l0   = lseg * 28;
        const int qb   = lseg * 14;
        float acc[28];
        const float bb = b2[co];
        #pragma unroll
        for (int j = 0; j < 28; ++j) acc[j] = bb;

        #pragma unroll 2
        for (int ci = 0; ci < 128; ++ci) {
            float tv[16];
            #pragma unroll
            for (int j = 0; j < 16; ++j) tv[j] = t1p[ci][qb + j];
            const float4 w = *reinterpret_cast<const float4*>(
                w2 + ((size_t)((ci << 6) + co) << 2));
            #pragma unroll
            for (int j = 0; j < 28; ++j) {
                const int qi = (j + 1) >> 1;
                const float wHI = (j & 1) ? w.x : w.y;
                const float wLO = (j & 1) ? w.z : w.w;
                acc[j] = fmaf(tv[qi + 1], wHI, acc[j]);
                acc[j] = fmaf(tv[qi],     wLO, acc[j]);
            }
        }
        const float s2 = sc2[co], h2 = sh2[co];
        #pragma unroll
        for (int j = 0; j < 28; ++j) {
            const int l = l0 + j;
            if (l < 108) t2p[co][l + 1] = fmaxf(fmaf(acc[j], s2, h2), 0.0f);
        }
    }
    __syncthreads();

    if (tid < 216) {
        const int l = tid;
        const int q = (l + 1) >> 1;
        const bool odd = (l & 1) != 0;
        float a = b3[0];
        #pragma unroll 4
        for (int ci = 0; ci < 64; ++ci) {
            const float4 w = *reinterpret_cast<const float4*>(w3 + ci * 4);
            const float wHI = odd ? w.x : w.y;
            const float wLO = odd ? w.z : w.w;
            a = fmaf(t2p[ci][q + 1], wHI, a);
            a = fmaf(t2p[ci][q],     wLO, a);
        }
        out[(size_t)b * 216 + l] = a;
    }
}

// ---------------------------------------------------------------------------
extern "C" void kernel_launch(void* const* d_in, const int* in_sizes, int n_in,
                              void* d_out, int out_size, void* d_ws, size_t ws_size,
                              hipStream_t stream) {
    const float* x     = (const float*)d_in[0];
    const float* h0f   = (const float*)d_in[1];
    const float* c0f   = (const float*)d_in[2];
    const float* h0b   = (const float*)d_in[3];
    const float* c0b   = (const float*)d_in[4];
    const float* h0m   = (const float*)d_in[5];
    const float* c0m   = (const float*)d_in[6];
    const float* Wih_f = (const float*)d_in[7];
    const float* Whh_f = (const float*)d_in[8];
    const float* bih_f = (const float*)d_in[9];
    const float* bhh_f = (const float*)d_in[10];
    const float* Wih_b = (const float*)d_in[11];
    const float* Whh_b = (const float*)d_in[12];
    const float* bih_b = (const float*)d_in[13];
    const float* bhh_b = (const float*)d_in[14];
    const float* Wih_m = (const float*)d_in[15];
    const float* Whh_m = (const float*)d_in[16];
    const float* bih_m = (const float*)d_in[17];
    const float* bhh_m = (const float*)d_in[18];
    const float* Wd    = (const float*)d_in[19];
    const float* bd    = (const float*)d_in[20];
    const float* w1    = (const float*)d_in[21];
    const float* b1    = (const float*)d_in[22];
    const float* w2    = (const float*)d_in[23];
    const float* b2    = (const float*)d_in[24];
    const float* w3    = (const float*)d_in[25];
    const float* b3    = (const float*)d_in[26];
    const float* g1    = (const float*)d_in[27];
    const float* be1   = (const float*)d_in[28];
    const float* m1    = (const float*)d_in[29];
    const float* v1    = (const float*)d_in[30];
    const float* g2    = (const float*)d_in[31];
    const float* be2   = (const float*)d_in[32];
    const float* m2    = (const float*)d_in[33];
    const float* v2    = (const float*)d_in[34];

    // ws layout (bytes), total 139,225,600 (proven fits):
    char* ws = (char*)d_ws;
    __hip_bfloat16* HF = (__hip_bfloat16*)ws;
    __hip_bfloat16* HB = (__hip_bfloat16*)(ws + 65536000);
    float* WihT_m = (float*)(ws + 131072000);
    float* WhhT_m = (float*)(ws + 131712000);
    float* WhhT_f = (float*)(ws + 132352000);
    float* WhhT_b = (float*)(ws + 132512000);
    __hip_bfloat16* HM = (__hip_bfloat16*)(ws + 132672000);

    k_prep<<<(160000 + 255) / 256, 256, 0, stream>>>(Wih_m, WihT_m, 200, 50, 160000);
    k_prep<<<(160000 + 255) / 256, 256, 0, stream>>>(Whh_m, WhhT_m, 200, 50, 160000);
    k_prep<<<(40000  + 255) / 256, 256, 0, stream>>>(Whh_f, WhhT_f, 100, 25, 40000);
    k_prep<<<(40000  + 255) / 256, 256, 0, stream>>>(Whh_b, WhhT_b, 100, 25, 40000);

    k_lstm100<<<dim3(256, 2), 512, 0, stream>>>(
        x, h0f, c0f, h0b, c0b,
        Wih_f, bih_f, bhh_f,
        Wih_b, bih_b, bhh_b,
        WhhT_f, WhhT_b, HF, HB);

    k_mid<<<1024, 512, 0, stream>>>(
        h0m, c0m, bih_m, bhh_m, WihT_m, WhhT_m, HF, HB, HM);

    k_head<<<16384, 256, 0, stream>>>(
        HM, Wd, bd, w1, b1, w2, b2, w3, b3,
        g1, be1, m1, v1, g2, be2, m2, v2, (float*)d_out);
}

// Round 10
// 11251.777 us; speedup vs baseline: 11.7598x; 2.8770x over previous
//
#include <hip/hip_runtime.h>
#include <hip/hip_bf16.h>

#define BTOT 16384

__device__ __forceinline__ float sig_(float x) {
    return __fdividef(1.0f, 1.0f + __expf(-x));
}
__device__ __forceinline__ float tanh_(float x) {
    float ax = fabsf(x);
    float e  = __expf(-2.0f * ax);
    float r  = __fdividef(1.0f - e, 1.0f + e);
    return x < 0.0f ? -r : r;
}

// ---------------------------------------------------------------------------
// Kernel 0: weight transpose. out[((u*K4+k4)*4+g)*4+j] = in[(g*U+u)*K + k4*4+j]
// ---------------------------------------------------------------------------
__global__ __launch_bounds__(256) void k_prep(
    const float* __restrict__ Win, float* __restrict__ Wout,
    int U, int K4, int n)
{
    const int e = blockIdx.x * 256 + threadIdx.x;
    if (e >= n) return;
    const int j  = e & 3;
    const int g  = (e >> 2) & 3;
    const int e4 = e >> 4;
    const int k4 = e4 % K4;
    const int u  = e4 / K4;
    const int K  = K4 * 4;
    Wout[e] = Win[(size_t)(g * U + u) * K + k4 * 4 + j];
}

// ---------------------------------------------------------------------------
// Kernel 1 (round-7 PROVEN): the two (5 -> 100) LSTMs. grid = (256, 2),
// block = 512, 8 WAVE-UNIFORM ragged unit-groups (4x13 + 4x12) x 64 rows.
// Wave-uniform weight addresses -> scalar-pipe loads (SGPRs), low VGPR.
// LDS = 35,456 B. Output H{F,B} bf16 [t][u][b].
// ---------------------------------------------------------------------------
__global__ __launch_bounds__(512, 4) void k_lstm100(
    const float* __restrict__ x,
    const float* __restrict__ h0f, const float* __restrict__ c0f,
    const float* __restrict__ h0b, const float* __restrict__ c0b,
    const float* __restrict__ WihF, const float* __restrict__ bihF,
    const float* __restrict__ bhhF,
    const float* __restrict__ WihB, const float* __restrict__ bihB,
    const float* __restrict__ bhhB,
    const float* __restrict__ WhhTF, const float* __restrict__ WhhTB,
    __hip_bfloat16* __restrict__ HF, __hip_bfloat16* __restrict__ HB)
{
    const int dir = blockIdx.y;
    const float* h0   = dir ? h0b   : h0f;
    const float* c0   = dir ? c0b   : c0f;
    const float* Wih  = dir ? WihB  : WihF;
    const float* bih  = dir ? bihB  : bihF;
    const float* bhh  = dir ? bhhB  : bhhF;
    const float* WhhT = dir ? WhhTB : WhhTF;
    __hip_bfloat16* Hout = dir ? HB : HF;

    __shared__ float h_s[64][101];
    __shared__ float wih_s[2000];
    __shared__ float bias_s[400];

    const int tid  = threadIdx.x;
    const int r    = tid & 63;
    const int ug   = __builtin_amdgcn_readfirstlane(tid >> 6);  // 0..7, uniform
    const int NU   = (ug < 4) ? 13 : 12;
    const int u0   = (ug < 4) ? ug * 13 : 52 + (ug - 4) * 12;
    const int rb   = blockIdx.x * 64;
    const int brow = rb + r;

    for (int i = tid; i < 2000; i += 512) wih_s[i] = Wih[i];
    for (int i = tid; i < 400;  i += 512) bias_s[i] = bih[i] + bhh[i];
    for (int i = tid; i < 6400; i += 512) h_s[i / 100][i % 100] = h0[(size_t)rb * 100 + i];

    float c[13];
    #pragma unroll
    for (int k = 0; k < 13; ++k)
        if (k < NU) c[k] = c0[(size_t)brow * 100 + u0 + k];
    __syncthreads();

    for (int t = 0; t < 20; ++t) {
        const int tt = dir ? (19 - t) : t;
        float xv[5];
        const float* xp = x + (size_t)tt * (BTOT * 5) + (size_t)brow * 5;
        #pragma unroll
        for (int i = 0; i < 5; ++i) xv[i] = xp[i];

        float acc[13][4];
        #pragma unroll
        for (int ju = 0; ju < 13; ++ju) {
            if (ju < NU) {
                #pragma unroll
                for (int g = 0; g < 4; ++g) {
                    const int row = g * 100 + u0 + ju;
                    float a = bias_s[row];
                    #pragma unroll
                    for (int i = 0; i < 5; ++i) a = fmaf(xv[i], wih_s[row * 5 + i], a);
                    acc[ju][g] = a;
                }
            }
        }

        #pragma unroll 1
        for (int i4 = 0; i4 < 25; ++i4) {
            const float hv0 = h_s[r][i4 * 4 + 0];
            const float hv1 = h_s[r][i4 * 4 + 1];
            const float hv2 = h_s[r][i4 * 4 + 2];
            const float hv3 = h_s[r][i4 * 4 + 3];
            #pragma unroll
            for (int ju = 0; ju < 13; ++ju) {
                if (ju < NU) {
                    const float* wp = WhhT + (((size_t)(u0 + ju) * 25 + i4) << 4);
                    #pragma unroll
                    for (int g = 0; g < 4; ++g) {
                        const float4 w = *reinterpret_cast<const float4*>(wp + g * 4);
                        float a = acc[ju][g];
                        a = fmaf(hv0, w.x, a); a = fmaf(hv1, w.y, a);
                        a = fmaf(hv2, w.z, a); a = fmaf(hv3, w.w, a);
                        acc[ju][g] = a;
                    }
                }
            }
        }

        float hnew[13];
        #pragma unroll
        for (int ju = 0; ju < 13; ++ju) {
            if (ju < NU) {
                const float ig = sig_(acc[ju][0]);
                const float fg = sig_(acc[ju][1]);
                const float gg = tanh_(acc[ju][2]);
                const float og = sig_(acc[ju][3]);
                const float cn = fmaf(fg, c[ju], ig * gg);
                c[ju] = cn;
                hnew[ju] = og * tanh_(cn);
            }
        }
        __syncthreads();
        #pragma unroll
        for (int k = 0; k < 13; ++k) {
            if (k < NU) {
                h_s[r][u0 + k] = hnew[k];
                Hout[((size_t)tt * 100 + u0 + k) * BTOT + brow] = __float2bfloat16(hnew[k]);
            }
        }
        __syncthreads();
    }
}

// ---------------------------------------------------------------------------
// Kernel 2 (round-7 PROVEN, verbatim): middle (200 -> 200) LSTM.
// grid = 256, block = 1024; 16 WAVE-UNIFORM ragged unit-groups (8x13+8x12)
// x 64 rows. Wave-uniform weight addrs -> scalar loads, VGPR ~60, no spill.
// LDS = 54,912 B. Final h -> HM bf16 [b][u].
// ---------------------------------------------------------------------------
__global__ __launch_bounds__(1024, 4) void k_mid(
    const float* __restrict__ h0m, const float* __restrict__ c0m,
    const float* __restrict__ bih, const float* __restrict__ bhh,
    const float* __restrict__ WihT, const float* __restrict__ WhhT,
    const __hip_bfloat16* __restrict__ HF, const __hip_bfloat16* __restrict__ HB,
    __hip_bfloat16* __restrict__ HM)
{
    __shared__ float bufA[64][101];   // hf[t], then hm 0..99
    __shared__ float bufB[64][101];   // hb[t], then hm 100..199
    __shared__ float bias_s[800];

    const int tid  = threadIdx.x;
    const int r    = tid & 63;
    const int ug   = __builtin_amdgcn_readfirstlane(tid >> 6);  // 0..15, uniform
    const int NU   = (ug < 8) ? 13 : 12;
    const int u0   = (ug < 8) ? ug * 13 : 104 + (ug - 8) * 12;
    const int rb   = blockIdx.x * 64;
    const int brow = rb + r;

    for (int i = tid; i < 800; i += 1024) bias_s[i] = bih[i] + bhh[i];

    float hm[13], cm[13];
    #pragma unroll
    for (int k = 0; k < 13; ++k) {
        if (k < NU) {
            hm[k] = h0m[(size_t)brow * 200 + u0 + k];
            cm[k] = c0m[(size_t)brow * 200 + u0 + k];
        }
    }
    __syncthreads();

    for (int t = 0; t < 20; ++t) {
        // ---- S1: stage hf[t] -> bufA, hb[t] -> bufB ----
        const __hip_bfloat16* HFt = HF + (size_t)t * 100 * BTOT + rb;
        const __hip_bfloat16* HBt = HB + (size_t)t * 100 * BTOT + rb;
        for (int i = tid; i < 6400; i += 1024) {
            const int rr = i & 63;
            const int u  = i >> 6;
            bufA[rr][u] = __bfloat162float(HFt[(size_t)u * BTOT + rr]);
            bufB[rr][u] = __bfloat162float(HBt[(size_t)u * BTOT + rr]);
        }
        __syncthreads();

        // ---- S2: acc = bias + WihT * [hf|hb] (k4 0..24 = hf, 25..49 = hb) ----
        float acc[13][4];
        #pragma unroll
        for (int ju = 0; ju < 13; ++ju)
            if (ju < NU)
                #pragma unroll
                for (int g = 0; g < 4; ++g)
                    acc[ju][g] = bias_s[g * 200 + u0 + ju];

        #pragma unroll 1
        for (int i4 = 0; i4 < 50; ++i4) {
            const float* hrow = (i4 < 25) ? &bufA[r][i4 * 4] : &bufB[r][(i4 - 25) * 4];
            const float hv0 = hrow[0];
            const float hv1 = hrow[1];
            const float hv2 = hrow[2];
            const float hv3 = hrow[3];
            #pragma unroll
            for (int ju = 0; ju < 13; ++ju) {
                if (ju < NU) {
                    const float* wp = WihT + (((size_t)(u0 + ju) * 50 + i4) << 4);
                    #pragma unroll
                    for (int g = 0; g < 4; ++g) {
                        float a = acc[ju][g];
                        a = fmaf(hv0, wp[g * 4 + 0], a);
                        a = fmaf(hv1, wp[g * 4 + 1], a);
                        a = fmaf(hv2, wp[g * 4 + 2], a);
                        a = fmaf(hv3, wp[g * 4 + 3], a);
                        acc[ju][g] = a;
                    }
                }
            }
        }
        __syncthreads();          // done reading hf/hb tiles

        // ---- S3: publish hm[t-1]: units 0..99 -> bufA, 100..199 -> bufB ----
        #pragma unroll
        for (int k = 0; k < 13; ++k) {
            if (k < NU) {
                const int u = u0 + k;
                if (u < 100) bufA[r][u] = hm[k];
                else         bufB[r][u - 100] = hm[k];
            }
        }
        __syncthreads();

        // ---- S4: acc += WhhT * hm; gates ----
        #pragma unroll 1
        for (int i4 = 0; i4 < 50; ++i4) {
            const float* hrow = (i4 < 25) ? &bufA[r][i4 * 4] : &bufB[r][(i4 - 25) * 4];
            const float hv0 = hrow[0];
            const float hv1 = hrow[1];
            const float hv2 = hrow[2];
            const float hv3 = hrow[3];
            #pragma unroll
            for (int ju = 0; ju < 13; ++ju) {
                if (ju < NU) {
                    const float* wp = WhhT + (((size_t)(u0 + ju) * 50 + i4) << 4);
                    #pragma unroll
                    for (int g = 0; g < 4; ++g) {
                        float a = acc[ju][g];
                        a = fmaf(hv0, wp[g * 4 + 0], a);
                        a = fmaf(hv1, wp[g * 4 + 1], a);
                        a = fmaf(hv2, wp[g * 4 + 2], a);
                        a = fmaf(hv3, wp[g * 4 + 3], a);
                        acc[ju][g] = a;
                    }
                }
            }
        }
        #pragma unroll
        for (int ju = 0; ju < 13; ++ju) {
            if (ju < NU) {
                const float ig = sig_(acc[ju][0]);
                const float fg = sig_(acc[ju][1]);
                const float gg = tanh_(acc[ju][2]);
                const float og = sig_(acc[ju][3]);
                const float cn = fmaf(fg, cm[ju], ig * gg);
                cm[ju] = cn;
                hm[ju] = og * tanh_(cn);
            }
        }
        __syncthreads();          // protect bufA/bufB before next S1
    }

    #pragma unroll
    for (int k = 0; k < 13; ++k)
        if (k < NU)
            HM[(size_t)brow * 200 + u0 + k] = __float2bfloat16(hm[k]);
}

// ---------------------------------------------------------------------------
// Kernel 3: dense + convT chain, zero-padded LDS tiles (round-8/9 proven).
// ---------------------------------------------------------------------------
__global__ __launch_bounds__(256, 2) void k_head(
    const __hip_bfloat16* __restrict__ HM,
    const float* __restrict__ Wd, const float* __restrict__ bd,
    const float* __restrict__ w1, const float* __restrict__ b1,
    const float* __restrict__ w2, const float* __restrict__ b2,
    const float* __restrict__ w3, const float* __restrict__ b3,
    const float* __restrict__ g1, const float* __restrict__ be1,
    const float* __restrict__ m1, const float* __restrict__ v1,
    const float* __restrict__ g2, const float* __restrict__ be2,
    const float* __restrict__ m2, const float* __restrict__ v2,
    float* __restrict__ out)
{
    __shared__ float hm_s[200];
    __shared__ float y27p[29];
    __shared__ float t1p[128][58];
    __shared__ float t2p[64][110];
    __shared__ float sc1[128], sh1[128], sc2[64], sh2[64];

    const int tid = threadIdx.x;
    const int b   = blockIdx.x;

    if (tid < 200) hm_s[tid] = __bfloat162float(HM[(size_t)b * 200 + tid]);
    if (tid < 128) {
        const float s = g1[tid] * __frsqrt_rn(v1[tid] + 1e-5f);
        sc1[tid] = s; sh1[tid] = be1[tid] - m1[tid] * s;
    } else if (tid < 192) {
        const int cc = tid - 128;
        const float s = g2[cc] * __frsqrt_rn(v2[cc] + 1e-5f);
        sc2[cc] = s; sh2[cc] = be2[cc] - m2[cc] * s;
    }
    {
        const int co = tid >> 1;
        t1p[co][(tid & 1) ? 55 : 0] = 0.0f;
        if (tid < 128) { t1p[tid][56] = 0.0f; t1p[tid][57] = 0.0f; }
        if (tid < 64)  { t2p[tid][0] = 0.0f; t2p[tid][109] = 0.0f; }
        if (tid == 0)  { y27p[0] = 0.0f; y27p[28] = 0.0f; }
    }
    __syncthreads();

    if (tid < 27) {
        float a = bd[tid];
        const float* wr = Wd + tid * 200;
        for (int i = 0; i < 200; ++i) a = fmaf(hm_s[i], wr[i], a);
        y27p[tid + 1] = a;
    }
    __syncthreads();

    for (int idx = tid; idx < 128 * 54; idx += 256) {
        const int co = idx / 54;
        const int l  = idx - co * 54;
        const int q  = (l + 1) >> 1;
        const float4 w = *reinterpret_cast<const float4*>(w1 + co * 4);
        const float wHI = (l & 1) ? w.x : w.y;
        const float wLO = (l & 1) ? w.z : w.w;
        float a = b1[co];
        a = fmaf(y27p[q + 1], wHI, a);
        a = fmaf(y27p[q],     wLO, a);
        a = fmaf(a, sc1[co], sh1[co]);
        t1p[co][l + 1] = fmaxf(a, 0.0f);
    }
    __syncthreads();

    {
        const int co   = tid & 63;
        const int lseg = tid >> 6;
        const int l0   = lseg * 28;
        const int qb   = lseg * 14;
        float acc[28];
        const float bb = b2[co];
        #pragma unroll
        for (int j = 0; j < 28; ++j) acc[j] = bb;

        #pragma unroll 2
        for (int ci = 0; ci < 128; ++ci) {
            float tv[16];
            #pragma unroll
            for (int j = 0; j < 16; ++j) tv[j] = t1p[ci][qb + j];
            const float4 w = *reinterpret_cast<const float4*>(
                w2 + ((size_t)((ci << 6) + co) << 2));
            #pragma unroll
            for (int j = 0; j < 28; ++j) {
                const int qi = (j + 1) >> 1;
                const float wHI = (j & 1) ? w.x : w.y;
                const float wLO = (j & 1) ? w.z : w.w;
                acc[j] = fmaf(tv[qi + 1], wHI, acc[j]);
                acc[j] = fmaf(tv[qi],     wLO, acc[j]);
            }
        }
        const float s2 = sc2[co], h2 = sh2[co];
        #pragma unroll
        for (int j = 0; j < 28; ++j) {
            const int l = l0 + j;
            if (l < 108) t2p[co][l + 1] = fmaxf(fmaf(acc[j], s2, h2), 0.0f);
        }
    }
    __syncthreads();

    if (tid < 216) {
        const int l = tid;
        const int q = (l + 1) >> 1;
        const bool odd = (l & 1) != 0;
        float a = b3[0];
        #pragma unroll 4
        for (int ci = 0; ci < 64; ++ci) {
            const float4 w = *reinterpret_cast<const float4*>(w3 + ci * 4);
            const float wHI = odd ? w.x : w.y;
            const float wLO = odd ? w.z : w.w;
            a = fmaf(t2p[ci][q + 1], wHI, a);
            a = fmaf(t2p[ci][q],     wLO, a);
        }
        out[(size_t)b * 216 + l] = a;
    }
}

// ---------------------------------------------------------------------------
extern "C" void kernel_launch(void* const* d_in, const int* in_sizes, int n_in,
                              void* d_out, int out_size, void* d_ws, size_t ws_size,
                              hipStream_t stream) {
    const float* x     = (const float*)d_in[0];
    const float* h0f   = (const float*)d_in[1];
    const float* c0f   = (const float*)d_in[2];
    const float* h0b   = (const float*)d_in[3];
    const float* c0b   = (const float*)d_in[4];
    const float* h0m   = (const float*)d_in[5];
    const float* c0m   = (const float*)d_in[6];
    const float* Wih_f = (const float*)d_in[7];
    const float* Whh_f = (const float*)d_in[8];
    const float* bih_f = (const float*)d_in[9];
    const float* bhh_f = (const float*)d_in[10];
    const float* Wih_b = (const float*)d_in[11];
    const float* Whh_b = (const float*)d_in[12];
    const float* bih_b = (const float*)d_in[13];
    const float* bhh_b = (const float*)d_in[14];
    const float* Wih_m = (const float*)d_in[15];
    const float* Whh_m = (const float*)d_in[16];
    const float* bih_m = (const float*)d_in[17];
    const float* bhh_m = (const float*)d_in[18];
    const float* Wd    = (const float*)d_in[19];
    const float* bd    = (const float*)d_in[20];
    const float* w1    = (const float*)d_in[21];
    const float* b1    = (const float*)d_in[22];
    const float* w2    = (const float*)d_in[23];
    const float* b2    = (const float*)d_in[24];
    const float* w3    = (const float*)d_in[25];
    const float* b3    = (const float*)d_in[26];
    const float* g1    = (const float*)d_in[27];
    const float* be1   = (const float*)d_in[28];
    const float* m1    = (const float*)d_in[29];
    const float* v1    = (const float*)d_in[30];
    const float* g2    = (const float*)d_in[31];
    const float* be2   = (const float*)d_in[32];
    const float* m2    = (const float*)d_in[33];
    const float* v2    = (const float*)d_in[34];

    // ws layout (bytes), total 139,225,600 (proven fits):
    char* ws = (char*)d_ws;
    __hip_bfloat16* HF = (__hip_bfloat16*)ws;
    __hip_bfloat16* HB = (__hip_bfloat16*)(ws + 65536000);
    float* WihT_m = (float*)(ws + 131072000);
    float* WhhT_m = (float*)(ws + 131712000);
    float* WhhT_f = (float*)(ws + 132352000);
    float* WhhT_b = (float*)(ws + 132512000);
    __hip_bfloat16* HM = (__hip_bfloat16*)(ws + 132672000);

    k_prep<<<(160000 + 255) / 256, 256, 0, stream>>>(Wih_m, WihT_m, 200, 50, 160000);
    k_prep<<<(160000 + 255) / 256, 256, 0, stream>>>(Whh_m, WhhT_m, 200, 50, 160000);
    k_prep<<<(40000  + 255) / 256, 256, 0, stream>>>(Whh_f, WhhT_f, 100, 25, 40000);
    k_prep<<<(40000  + 255) / 256, 256, 0, stream>>>(Whh_b, WhhT_b, 100, 25, 40000);

    k_lstm100<<<dim3(256, 2), 512, 0, stream>>>(
        x, h0f, c0f, h0b, c0b,
        Wih_f, bih_f, bhh_f,
        Wih_b, bih_b, bhh_b,
        WhhT_f, WhhT_b, HF, HB);

    k_mid<<<256, 1024, 0, stream>>>(
        h0m, c0m, bih_m, bhh_m, WihT_m, WhhT_m, HF, HB, HM);

    k_head<<<16384, 256, 0, stream>>>(
        HM, Wd, bd, w1, b1, w2, b2, w3, b3,
        g1, be1, m1, v1, g2, be2, m2, v2, (float*)d_out);
}

// Round 11
// 6376.650 us; speedup vs baseline: 20.7505x; 1.7645x over previous
//
#include <hip/hip_runtime.h>
#include <hip/hip_bf16.h>

#define BTOT 16384

typedef __attribute__((ext_vector_type(8))) short bf16x8;
typedef __attribute__((ext_vector_type(4))) float f32x4;

__device__ __forceinline__ float sig_(float x) {
    return __fdividef(1.0f, 1.0f + __expf(-x));
}
__device__ __forceinline__ float tanh_(float x) {
    float ax = fabsf(x);
    float e  = __expf(-2.0f * ax);
    float r  = __fdividef(1.0f - e, 1.0f + e);
    return x < 0.0f ? -r : r;
}

// ---------------------------------------------------------------------------
// Kernel 0a: weight transpose for the 100-LSTMs (round-7 proven).
// ---------------------------------------------------------------------------
__global__ __launch_bounds__(256) void k_prep(
    const float* __restrict__ Win, float* __restrict__ Wout,
    int U, int K4, int n)
{
    const int e = blockIdx.x * 256 + threadIdx.x;
    if (e >= n) return;
    const int j  = e & 3;
    const int g  = (e >> 2) & 3;
    const int e4 = e >> 4;
    const int k4 = e4 % K4;
    const int u  = e4 / K4;
    const int K  = K4 * 4;
    Wout[e] = Win[(size_t)(g * U + u) * K + k4 * 4 + j];
}

// ---------------------------------------------------------------------------
// Kernel 0b: build MFMA B-fragments for k_mid. Combined W[416][800]:
// rows 0-199 = Wih_m^T, 200-399 = Whh_m^T, 400-414 = 0, 415 = bias (A col
// 415 is 1.0 -> bias fused into GEMM). Outputs permuted o' = u*4 + g.
// Fragment order: e = ((ct*13+kt)*64 + lane)*8 + j, element (k,o') with
// k = kt*32 + (lane>>4)*8 + j, o' = ct*16 + (lane&15). Split hi/lo bf16.
// ---------------------------------------------------------------------------
__global__ __launch_bounds__(256) void k_prep_mfma(
    const float* __restrict__ Wih, const float* __restrict__ Whh,
    const float* __restrict__ bih, const float* __restrict__ bhh,
    __hip_bfloat16* __restrict__ Bhi, __hip_bfloat16* __restrict__ Blo)
{
    const int e = blockIdx.x * 256 + threadIdx.x;
    if (e >= 332800) return;
    const int j  = e & 7;
    const int l  = (e >> 3) & 63;
    const int r2 = e >> 9;             // ct*13 + kt
    const int kt = r2 % 13;
    const int ct = r2 / 13;
    const int k  = kt * 32 + ((l >> 4) << 3) + j;
    const int op = ct * 16 + (l & 15); // o' = u*4 + g
    const int u  = op >> 2;
    const int g  = op & 3;
    const int row = g * 200 + u;       // original gate-major row
    float val;
    if (k < 200)       val = Wih[(size_t)row * 200 + k];
    else if (k < 400)  val = Whh[(size_t)row * 200 + (k - 200)];
    else if (k == 415) val = bih[row] + bhh[row];
    else               val = 0.0f;
    const __hip_bfloat16 hi = __float2bfloat16(val);
    Bhi[e] = hi;
    Blo[e] = __float2bfloat16(val - __bfloat162float(hi));
}

// ---------------------------------------------------------------------------
// Kernel 1 (round-7/10 PROVEN): the two (5 -> 100) LSTMs. grid = (256, 2),
// block = 512, 8 wave-uniform ragged unit-groups. LDS = 35,456 B.
// ---------------------------------------------------------------------------
__global__ __launch_bounds__(512, 4) void k_lstm100(
    const float* __restrict__ x,
    const float* __restrict__ h0f, const float* __restrict__ c0f,
    const float* __restrict__ h0b, const float* __restrict__ c0b,
    const float* __restrict__ WihF, const float* __restrict__ bihF,
    const float* __restrict__ bhhF,
    const float* __restrict__ WihB, const float* __restrict__ bihB,
    const float* __restrict__ bhhB,
    const float* __restrict__ WhhTF, const float* __restrict__ WhhTB,
    __hip_bfloat16* __restrict__ HF, __hip_bfloat16* __restrict__ HB)
{
    const int dir = blockIdx.y;
    const float* h0   = dir ? h0b   : h0f;
    const float* c0   = dir ? c0b   : c0f;
    const float* Wih  = dir ? WihB  : WihF;
    const float* bih  = dir ? bihB  : bihF;
    const float* bhh  = dir ? bhhB  : bhhF;
    const float* WhhT = dir ? WhhTB : WhhTF;
    __hip_bfloat16* Hout = dir ? HB : HF;

    __shared__ float h_s[64][101];
    __shared__ float wih_s[2000];
    __shared__ float bias_s[400];

    const int tid  = threadIdx.x;
    const int r    = tid & 63;
    const int ug   = __builtin_amdgcn_readfirstlane(tid >> 6);  // 0..7, uniform
    const int NU   = (ug < 4) ? 13 : 12;
    const int u0   = (ug < 4) ? ug * 13 : 52 + (ug - 4) * 12;
    const int rb   = blockIdx.x * 64;
    const int brow = rb + r;

    for (int i = tid; i < 2000; i += 512) wih_s[i] = Wih[i];
    for (int i = tid; i < 400;  i += 512) bias_s[i] = bih[i] + bhh[i];
    for (int i = tid; i < 6400; i += 512) h_s[i / 100][i % 100] = h0[(size_t)rb * 100 + i];

    float c[13];
    #pragma unroll
    for (int k = 0; k < 13; ++k)
        if (k < NU) c[k] = c0[(size_t)brow * 100 + u0 + k];
    __syncthreads();

    for (int t = 0; t < 20; ++t) {
        const int tt = dir ? (19 - t) : t;
        float xv[5];
        const float* xp = x + (size_t)tt * (BTOT * 5) + (size_t)brow * 5;
        #pragma unroll
        for (int i = 0; i < 5; ++i) xv[i] = xp[i];

        float acc[13][4];
        #pragma unroll
        for (int ju = 0; ju < 13; ++ju) {
            if (ju < NU) {
                #pragma unroll
                for (int g = 0; g < 4; ++g) {
                    const int row = g * 100 + u0 + ju;
                    float a = bias_s[row];
                    #pragma unroll
                    for (int i = 0; i < 5; ++i) a = fmaf(xv[i], wih_s[row * 5 + i], a);
                    acc[ju][g] = a;
                }
            }
        }

        #pragma unroll 1
        for (int i4 = 0; i4 < 25; ++i4) {
            const float hv0 = h_s[r][i4 * 4 + 0];
            const float hv1 = h_s[r][i4 * 4 + 1];
            const float hv2 = h_s[r][i4 * 4 + 2];
            const float hv3 = h_s[r][i4 * 4 + 3];
            #pragma unroll
            for (int ju = 0; ju < 13; ++ju) {
                if (ju < NU) {
                    const float* wp = WhhT + (((size_t)(u0 + ju) * 25 + i4) << 4);
                    #pragma unroll
                    for (int g = 0; g < 4; ++g) {
                        const float4 w = *reinterpret_cast<const float4*>(wp + g * 4);
                        float a = acc[ju][g];
                        a = fmaf(hv0, w.x, a); a = fmaf(hv1, w.y, a);
                        a = fmaf(hv2, w.z, a); a = fmaf(hv3, w.w, a);
                        acc[ju][g] = a;
                    }
                }
            }
        }

        float hnew[13];
        #pragma unroll
        for (int ju = 0; ju < 13; ++ju) {
            if (ju < NU) {
                const float ig = sig_(acc[ju][0]);
                const float fg = sig_(acc[ju][1]);
                const float gg = tanh_(acc[ju][2]);
                const float og = sig_(acc[ju][3]);
                const float cn = fmaf(fg, c[ju], ig * gg);
                c[ju] = cn;
                hnew[ju] = og * tanh_(cn);
            }
        }
        __syncthreads();
        #pragma unroll
        for (int k = 0; k < 13; ++k) {
            if (k < NU) {
                h_s[r][u0 + k] = hnew[k];
                Hout[((size_t)tt * 100 + u0 + k) * BTOT + brow] = __float2bfloat16(hnew[k]);
            }
        }
        __syncthreads();
    }
}

// ---------------------------------------------------------------------------
// Kernel 2: MFMA middle LSTM. grid = 256, block = 512 (8 waves), 64 rows.
// A-tile [64][424] bf16 in LDS: cols 0-99 hf[t], 100-199 hb[t],
// 200-399 hm[t-1], 400-414 zero, 415 = 1.0 (bias row in B).
// Per step: G = A x W via mfma_f32_16x16x32_bf16 (hi+lo weight split);
// wave w handles row-tiles 0-3 x cts {w, w+8, ...}. Gates via per-wave
// LDS transpose scratch; c in registers. LDS = 62,976 B.
// ---------------------------------------------------------------------------
__global__ __launch_bounds__(512, 2) void k_mid(
    const float* __restrict__ h0m, const float* __restrict__ c0m,
    const __hip_bfloat16* __restrict__ Bhi, const __hip_bfloat16* __restrict__ Blo,
    const __hip_bfloat16* __restrict__ HF, const __hip_bfloat16* __restrict__ HB,
    __hip_bfloat16* __restrict__ HM)
{
    __shared__ __hip_bfloat16 At[64][424];   // 54,272 B (stride 848 B: 16B-aligned rows)
    __shared__ float scr[8][16][17];         //  8,704 B per-wave transpose scratch

    const int tid = threadIdx.x;
    const int l   = tid & 63;
    const int w   = tid >> 6;                // wave 0..7
    const int rb  = blockIdx.x * 64;

    // ---- c0 into registers: lane owns (row 16rt+(l>>2), unit ct*4+(l&3)) ----
    float cst[7][4], hval[7][4];
    #pragma unroll
    for (int cti = 0; cti < 7; ++cti) {
        const int ct = w + 8 * cti;
        if (ct < 50) {
            #pragma unroll
            for (int rt = 0; rt < 4; ++rt) {
                const int row = rb + rt * 16 + (l >> 2);
                cst[cti][rt] = c0m[(size_t)row * 200 + ct * 4 + (l & 3)];
            }
        }
    }

    // ---- init A: hm = bf16(h0m); pad cols; hf/hb[0] ----
    for (int i = tid; i < 12800; i += 512) {
        const int u = i % 200, rr = i / 200;
        At[rr][200 + u] = __float2bfloat16(h0m[(size_t)(rb + rr) * 200 + u]);
    }
    for (int i = tid; i < 1024; i += 512) {
        const int rr = i >> 4, cc = i & 15;
        At[rr][400 + cc] = __float2bfloat16((cc == 15) ? 1.0f : 0.0f);
    }
    for (int i = tid; i < 6400; i += 512) {
        const int rr = i & 63, u = i >> 6;
        At[rr][u]       = HF[(size_t)u * BTOT + rb + rr];
        At[rr][100 + u] = HB[(size_t)u * BTOT + rb + rr];
    }
    __syncthreads();

    for (int t = 0; t < 20; ++t) {
        #pragma unroll
        for (int cti = 0; cti < 7; ++cti) {
            const int ct = w + 8 * cti;
            if (ct < 50) {
                f32x4 acc[4];
                #pragma unroll
                for (int rt = 0; rt < 4; ++rt) acc[rt] = (f32x4){0.f, 0.f, 0.f, 0.f};
                const __hip_bfloat16* bph = Bhi + ((size_t)ct * 13 * 64 + l) * 8;
                const __hip_bfloat16* bpl = Blo + ((size_t)ct * 13 * 64 + l) * 8;
                const int arow = l & 15;
                const int koff = (l >> 4) * 8;
                #pragma unroll
                for (int kt = 0; kt < 13; ++kt) {
                    const bf16x8 bh = *reinterpret_cast<const bf16x8*>(bph + kt * 512);
                    const bf16x8 bl = *reinterpret_cast<const bf16x8*>(bpl + kt * 512);
                    const int ko = kt * 32 + koff;
                    #pragma unroll
                    for (int rt = 0; rt < 4; ++rt) {
                        const bf16x8 a = *reinterpret_cast<const bf16x8*>(&At[rt * 16 + arow][ko]);
                        acc[rt] = __builtin_amdgcn_mfma_f32_16x16x32_bf16(a, bh, acc[rt], 0, 0, 0);
                        acc[rt] = __builtin_amdgcn_mfma_f32_16x16x32_bf16(a, bl, acc[rt], 0, 0, 0);
                    }
                }
                // gates for this ct (wave-local transpose via scratch)
                #pragma unroll
                for (int rt = 0; rt < 4; ++rt) {
                    #pragma unroll
                    for (int rr = 0; rr < 4; ++rr)
                        scr[w][(l >> 4) * 4 + rr][l & 15] = acc[rt][rr];
                    const float g0 = scr[w][l >> 2][(l & 3) * 4 + 0];
                    const float g1 = scr[w][l >> 2][(l & 3) * 4 + 1];
                    const float g2 = scr[w][l >> 2][(l & 3) * 4 + 2];
                    const float g3 = scr[w][l >> 2][(l & 3) * 4 + 3];
                    const float ig = sig_(g0);
                    const float fg = sig_(g1);
                    const float gg = tanh_(g2);
                    const float og = sig_(g3);
                    const float cn = fmaf(fg, cst[cti][rt], ig * gg);
                    cst[cti][rt] = cn;
                    hval[cti][rt] = og * tanh_(cn);
                }
            }
        }
        __syncthreads();           // all waves done reading A for step t

        // publish hm[t] into A cols 200-399
        #pragma unroll
        for (int cti = 0; cti < 7; ++cti) {
            const int ct = w + 8 * cti;
            if (ct < 50) {
                #pragma unroll
                for (int rt = 0; rt < 4; ++rt)
                    At[rt * 16 + (l >> 2)][200 + ct * 4 + (l & 3)] =
                        __float2bfloat16(hval[cti][rt]);
            }
        }
        // stage hf/hb[t+1] into cols 0-199
        if (t < 19) {
            const __hip_bfloat16* HFt = HF + (size_t)(t + 1) * 100 * BTOT + rb;
            const __hip_bfloat16* HBt = HB + (size_t)(t + 1) * 100 * BTOT + rb;
            for (int i = tid; i < 6400; i += 512) {
                const int rr = i & 63, u = i >> 6;
                At[rr][u]       = HFt[(size_t)u * BTOT + rr];
                At[rr][100 + u] = HBt[(size_t)u * BTOT + rr];
            }
        }
        __syncthreads();
    }

    // final h -> HM bf16 [b][u] (coalesced over u)
    for (int i = tid; i < 12800; i += 512) {
        const int u = i % 200, rr = i / 200;
        HM[(size_t)(rb + rr) * 200 + u] = At[rr][200 + u];
    }
}

// ---------------------------------------------------------------------------
// Kernel 3: dense + convT chain, zero-padded LDS tiles (round-8/9/10 proven).
// ---------------------------------------------------------------------------
__global__ __launch_bounds__(256, 2) void k_head(
    const __hip_bfloat16* __restrict__ HM,
    const float* __restrict__ Wd, const float* __restrict__ bd,
    const float* __restrict__ w1, const float* __restrict__ b1,
    const float* __restrict__ w2, const float* __restrict__ b2,
    const float* __restrict__ w3, const float* __restrict__ b3,
    const float* __restrict__ g1, const float* __restrict__ be1,
    const float* __restrict__ m1, const float* __restrict__ v1,
    const float* __restrict__ g2, const float* __restrict__ be2,
    const float* __restrict__ m2, const float* __restrict__ v2,
    float* __restrict__ out)
{
    __shared__ float hm_s[200];
    __shared__ float y27p[29];
    __shared__ float t1p[128][58];
    __shared__ float t2p[64][110];
    __shared__ float sc1[128], sh1[128], sc2[64], sh2[64];

    const int tid = threadIdx.x;
    const int b   = blockIdx.x;

    if (tid < 200) hm_s[tid] = __bfloat162float(HM[(size_t)b * 200 + tid]);
    if (tid < 128) {
        const float s = g1[tid] * __frsqrt_rn(v1[tid] + 1e-5f);
        sc1[tid] = s; sh1[tid] = be1[tid] - m1[tid] * s;
    } else if (tid < 192) {
        const int cc = tid - 128;
        const float s = g2[cc] * __frsqrt_rn(v2[cc] + 1e-5f);
        sc2[cc] = s; sh2[cc] = be2[cc] - m2[cc] * s;
    }
    {
        const int co = tid >> 1;
        t1p[co][(tid & 1) ? 55 : 0] = 0.0f;
        if (tid < 128) { t1p[tid][56] = 0.0f; t1p[tid][57] = 0.0f; }
        if (tid < 64)  { t2p[tid][0] = 0.0f; t2p[tid][109] = 0.0f; }
        if (tid == 0)  { y27p[0] = 0.0f; y27p[28] = 0.0f; }
    }
    __syncthreads();

    if (tid < 27) {
        float a = bd[tid];
        const float* wr = Wd + tid * 200;
        for (int i = 0; i < 200; ++i) a = fmaf(hm_s[i], wr[i], a);
        y27p[tid + 1] = a;
    }
    __syncthreads();

    for (int idx = tid; idx < 128 * 54; idx += 256) {
        const int co = idx / 54;
        const int ll = idx - co * 54;
        const int q  = (ll + 1) >> 1;
        const float4 w = *reinterpret_cast<const float4*>(w1 + co * 4);
        const float wHI = (ll & 1) ? w.x : w.y;
        const float wLO = (ll & 1) ? w.z : w.w;
        float a = b1[co];
        a = fmaf(y27p[q + 1], wHI, a);
        a = fmaf(y27p[q],     wLO, a);
        a = fmaf(a, sc1[co], sh1[co]);
        t1p[co][ll + 1] = fmaxf(a, 0.0f);
    }
    __syncthreads();

    {
        const int co   = tid & 63;
        const int lseg = tid >> 6;
        const int l0   = lseg * 28;
        const int qb   = lseg * 14;
        float acc[28];
        const float bb = b2[co];
        #pragma unroll
        for (int j = 0; j < 28; ++j) acc[j] = bb;

        #pragma unroll 2
        for (int ci = 0; ci < 128; ++ci) {
            float tv[16];
            #pragma unroll
            for (int j = 0; j < 16; ++j) tv[j] = t1p[ci][qb + j];
            const float4 w = *reinterpret_cast<const float4*>(
                w2 + ((size_t)((ci << 6) + co) << 2));
            #pragma unroll
            for (int j = 0; j < 28; ++j) {
                const int qi = (j + 1) >> 1;
                const float wHI = (j & 1) ? w.x : w.y;
                const float wLO = (j & 1) ? w.z : w.w;
                acc[j] = fmaf(tv[qi + 1], wHI, acc[j]);
                acc[j] = fmaf(tv[qi],     wLO, acc[j]);
            }
        }
        const float s2 = sc2[co], h2 = sh2[co];
        #pragma unroll
        for (int j = 0; j < 28; ++j) {
            const int ll = l0 + j;
            if (ll < 108) t2p[co][ll + 1] = fmaxf(fmaf(acc[j], s2, h2), 0.0f);
        }
    }
    __syncthreads();

    if (tid < 216) {
        const int ll = tid;
        const int q = (ll + 1) >> 1;
        const bool odd = (ll & 1) != 0;
        float a = b3[0];
        #pragma unroll 4
        for (int ci = 0; ci < 64; ++ci) {
            const float4 w = *reinterpret_cast<const float4*>(w3 + ci * 4);
            const float wHI = odd ? w.x : w.y;
            const float wLO = odd ? w.z : w.w;
            a = fmaf(t2p[ci][q + 1], wHI, a);
            a = fmaf(t2p[ci][q],     wLO, a);
        }
        out[(size_t)b * 216 + ll] = a;
    }
}

// ---------------------------------------------------------------------------
extern "C" void kernel_launch(void* const* d_in, const int* in_sizes, int n_in,
                              void* d_out, int out_size, void* d_ws, size_t ws_size,
                              hipStream_t stream) {
    const float* x     = (const float*)d_in[0];
    const float* h0f   = (const float*)d_in[1];
    const float* c0f   = (const float*)d_in[2];
    const float* h0b   = (const float*)d_in[3];
    const float* c0b   = (const float*)d_in[4];
    const float* h0m   = (const float*)d_in[5];
    const float* c0m   = (const float*)d_in[6];
    const float* Wih_f = (const float*)d_in[7];
    const float* Whh_f = (const float*)d_in[8];
    const float* bih_f = (const float*)d_in[9];
    const float* bhh_f = (const float*)d_in[10];
    const float* Wih_b = (const float*)d_in[11];
    const float* Whh_b = (const float*)d_in[12];
    const float* bih_b = (const float*)d_in[13];
    const float* bhh_b = (const float*)d_in[14];
    const float* Wih_m = (const float*)d_in[15];
    const float* Whh_m = (const float*)d_in[16];
    const float* bih_m = (const float*)d_in[17];
    const float* bhh_m = (const float*)d_in[18];
    const float* Wd    = (const float*)d_in[19];
    const float* bd    = (const float*)d_in[20];
    const float* w1    = (const float*)d_in[21];
    const float* b1    = (const float*)d_in[22];
    const float* w2    = (const float*)d_in[23];
    const float* b2    = (const float*)d_in[24];
    const float* w3    = (const float*)d_in[25];
    const float* b3    = (const float*)d_in[26];
    const float* g1    = (const float*)d_in[27];
    const float* be1   = (const float*)d_in[28];
    const float* m1    = (const float*)d_in[29];
    const float* v1    = (const float*)d_in[30];
    const float* g2    = (const float*)d_in[31];
    const float* be2   = (const float*)d_in[32];
    const float* m2    = (const float*)d_in[33];
    const float* v2    = (const float*)d_in[34];

    // ws layout (bytes), total 139,276,800 <= proven 144,179,200:
    //   HF bf16 [20][100][16384]  @ 0            (65,536,000)
    //   HB bf16 [20][100][16384]  @ 65,536,000   (65,536,000)
    //   Bhi bf16 [332800]         @ 131,072,000  (665,600)
    //   Blo bf16 [332800]         @ 131,737,600  (665,600)
    //   WhhT_f f32 [40000]        @ 132,403,200  (160,000)
    //   WhhT_b f32 [40000]        @ 132,563,200  (160,000)
    //   HM bf16 [16384][200]      @ 132,723,200  (6,553,600)
    char* ws = (char*)d_ws;
    __hip_bfloat16* HF = (__hip_bfloat16*)ws;
    __hip_bfloat16* HB = (__hip_bfloat16*)(ws + 65536000);
    __hip_bfloat16* Bhi = (__hip_bfloat16*)(ws + 131072000);
    __hip_bfloat16* Blo = (__hip_bfloat16*)(ws + 131737600);
    float* WhhT_f = (float*)(ws + 132403200);
    float* WhhT_b = (float*)(ws + 132563200);
    __hip_bfloat16* HM = (__hip_bfloat16*)(ws + 132723200);

    k_prep<<<(40000 + 255) / 256, 256, 0, stream>>>(Whh_f, WhhT_f, 100, 25, 40000);
    k_prep<<<(40000 + 255) / 256, 256, 0, stream>>>(Whh_b, WhhT_b, 100, 25, 40000);
    k_prep_mfma<<<(332800 + 255) / 256, 256, 0, stream>>>(
        Wih_m, Whh_m, bih_m, bhh_m, Bhi, Blo);

    k_lstm100<<<dim3(256, 2), 512, 0, stream>>>(
        x, h0f, c0f, h0b, c0b,
        Wih_f, bih_f, bhh_f,
        Wih_b, bih_b, bhh_b,
        WhhT_f, WhhT_b, HF, HB);

    k_mid<<<256, 512, 0, stream>>>(
        h0m, c0m, Bhi, Blo, HF, HB, HM);

    k_head<<<16384, 256, 0, stream>>>(
        HM, Wd, bd, w1, b1, w2, b2, w3, b3,
        g1, be1, m1, v1, g2, be2, m2, v2, (float*)d_out);
}

// Round 12
// 2960.531 us; speedup vs baseline: 44.6943x; 2.1539x over previous
//
#include <hip/hip_runtime.h>
#include <hip/hip_bf16.h>

#define BTOT 16384

typedef __attribute__((ext_vector_type(8))) short bf16x8;
typedef __attribute__((ext_vector_type(4))) float f32x4;

__device__ __forceinline__ float sig_(float x) {
    return __fdividef(1.0f, 1.0f + __expf(-x));
}
__device__ __forceinline__ float tanh_(float x) {
    float ax = fabsf(x);
    float e  = __expf(-2.0f * ax);
    float r  = __fdividef(1.0f - e, 1.0f + e);
    return x < 0.0f ? -r : r;
}

// ---------------------------------------------------------------------------
// Kernel 0a: MFMA B-fragments for k_mid (round-11 PROVEN). W[416][800]:
// rows 0-199 Wih^T, 200-399 Whh^T, 400-414 zero, 415 bias. o' = u*4+g.
// e = ((ct*13+kt)*64 + lane)*8 + j; k = kt*32+(lane>>4)*8+j; o' = ct*16+(lane&15).
// ---------------------------------------------------------------------------
__global__ __launch_bounds__(256) void k_prep_mfma(
    const float* __restrict__ Wih, const float* __restrict__ Whh,
    const float* __restrict__ bih, const float* __restrict__ bhh,
    __hip_bfloat16* __restrict__ Bhi, __hip_bfloat16* __restrict__ Blo)
{
    const int e = blockIdx.x * 256 + threadIdx.x;
    if (e >= 332800) return;
    const int j  = e & 7;
    const int l  = (e >> 3) & 63;
    const int r2 = e >> 9;             // ct*13 + kt
    const int kt = r2 % 13;
    const int ct = r2 / 13;
    const int k  = kt * 32 + ((l >> 4) << 3) + j;
    const int op = ct * 16 + (l & 15);
    const int u  = op >> 2;
    const int g  = op & 3;
    const int row = g * 200 + u;
    float val;
    if (k < 200)       val = Wih[(size_t)row * 200 + k];
    else if (k < 400)  val = Whh[(size_t)row * 200 + (k - 200)];
    else if (k == 415) val = bih[row] + bhh[row];
    else               val = 0.0f;
    const __hip_bfloat16 hi = __float2bfloat16(val);
    Bhi[e] = hi;
    Blo[e] = __float2bfloat16(val - __bfloat162float(hi));
}

// ---------------------------------------------------------------------------
// Kernel 0b: MFMA B-fragments for the 100-LSTMs. Combined W[128][400]:
// A cols: 0-4 x_hi, 5-9 x_lo (both map to Wih rows), 10-109 h -> Whh,
// 110 bias, 111-127 zero. o' = u*4+g, row = g*100+u.
// e = ((ct*4+kt)*64 + lane)*8 + j, ct in 0..24, kt in 0..3. n = 51,200.
// ---------------------------------------------------------------------------
__global__ __launch_bounds__(256) void k_prep_mfma100(
    const float* __restrict__ Wih, const float* __restrict__ Whh,
    const float* __restrict__ bih, const float* __restrict__ bhh,
    __hip_bfloat16* __restrict__ Bhi, __hip_bfloat16* __restrict__ Blo)
{
    const int e = blockIdx.x * 256 + threadIdx.x;
    if (e >= 51200) return;
    const int j  = e & 7;
    const int l  = (e >> 3) & 63;
    const int r2 = e >> 9;             // ct*4 + kt
    const int kt = r2 & 3;
    const int ct = r2 >> 2;
    const int k  = kt * 32 + ((l >> 4) << 3) + j;
    const int op = ct * 16 + (l & 15);
    const int u  = op >> 2;
    const int g  = op & 3;
    const int row = g * 100 + u;
    float val;
    if (k < 5)         val = Wih[(size_t)row * 5 + k];
    else if (k < 10)   val = Wih[(size_t)row * 5 + (k - 5)];
    else if (k < 110)  val = Whh[(size_t)row * 100 + (k - 10)];
    else if (k == 110) val = bih[row] + bhh[row];
    else               val = 0.0f;
    const __hip_bfloat16 hi = __float2bfloat16(val);
    Bhi[e] = hi;
    Blo[e] = __float2bfloat16(val - __bfloat162float(hi));
}

// ---------------------------------------------------------------------------
// Kernel 1: MFMA 100-LSTMs. grid = (256, 2), block = 512 (8 waves), 64 rows.
// A-tile [64][136] bf16: cols 0-4 x_hi[t], 5-9 x_lo[t], 10-109 h, 110 = 1.0,
// 111-135 zero/pad. G = A x W via mfma_f32_16x16x32_bf16 (hi+lo weights).
// Wave w owns cts {w, w+8, w+16, w+24} (<25), all 4 row-tiles.
// Gates via per-wave scr transpose (k_mid-proven). LDS = 26,112 B.
// ---------------------------------------------------------------------------
__global__ __launch_bounds__(512, 2) void k_lstm100(
    const float* __restrict__ x,
    const float* __restrict__ h0f, const float* __restrict__ c0f,
    const float* __restrict__ h0b, const float* __restrict__ c0b,
    const __hip_bfloat16* __restrict__ BFhi, const __hip_bfloat16* __restrict__ BFlo,
    const __hip_bfloat16* __restrict__ BBhi, const __hip_bfloat16* __restrict__ BBlo,
    __hip_bfloat16* __restrict__ HF, __hip_bfloat16* __restrict__ HB)
{
    __shared__ __hip_bfloat16 At[64][136];   // 17,408 B (row stride 272 B)
    __shared__ float scr[8][16][17];         //  8,704 B

    const int dir = blockIdx.y;
    const float* h0 = dir ? h0b : h0f;
    const float* c0 = dir ? c0b : c0f;
    const __hip_bfloat16* Bhi = dir ? BBhi : BFhi;
    const __hip_bfloat16* Blo = dir ? BBlo : BFlo;
    __hip_bfloat16* Hout = dir ? HB : HF;

    const int tid = threadIdx.x;
    const int l   = tid & 63;
    const int w   = tid >> 6;                // wave 0..7
    const int rb  = blockIdx.x * 64;

    // c state: lane owns (row rt*16 + (l>>2), unit ct*4 + (l&3))
    float cst[4][4];
    #pragma unroll
    for (int cti = 0; cti < 4; ++cti) {
        const int ct = w + 8 * cti;
        if (ct < 25) {
            #pragma unroll
            for (int rt = 0; rt < 4; ++rt)
                cst[cti][rt] = c0[(size_t)(rb + rt * 16 + (l >> 2)) * 100 + ct * 4 + (l & 3)];
        }
    }

    // init A: h0 -> cols 10..109; col 110 = 1.0; 111..135 = 0; x[t0] -> 0..9
    for (int i = tid; i < 6400; i += 512) {
        const int row = i / 100, u = i - row * 100;
        At[row][10 + u] = __float2bfloat16(h0[(size_t)(rb + row) * 100 + u]);
    }
    for (int i = tid; i < 64 * 26; i += 512) {
        const int row = i / 26, cc = i - row * 26;
        At[row][110 + cc] = __float2bfloat16(cc == 0 ? 1.0f : 0.0f);
    }
    {
        const int tt0 = dir ? 19 : 0;
        if (tid < 320) {
            const float v = x[(size_t)tt0 * (BTOT * 5) + (size_t)rb * 5 + tid];
            const int row = tid / 5, cc = tid - row * 5;
            const __hip_bfloat16 hi = __float2bfloat16(v);
            At[row][cc]     = hi;
            At[row][5 + cc] = __float2bfloat16(v - __bfloat162float(hi));
        }
    }
    __syncthreads();

    for (int t = 0; t < 20; ++t) {
        const int tt = dir ? (19 - t) : t;

        f32x4 acc[4][4];
        #pragma unroll
        for (int cti = 0; cti < 4; ++cti)
            #pragma unroll
            for (int rt = 0; rt < 4; ++rt)
                acc[cti][rt] = (f32x4){0.f, 0.f, 0.f, 0.f};

        #pragma unroll
        for (int kt = 0; kt < 4; ++kt) {
            bf16x8 afr[4];
            #pragma unroll
            for (int rt = 0; rt < 4; ++rt)
                afr[rt] = *reinterpret_cast<const bf16x8*>(
                    &At[rt * 16 + (l & 15)][kt * 32 + (l >> 4) * 8]);
            #pragma unroll
            for (int cti = 0; cti < 4; ++cti) {
                const int ct = w + 8 * cti;
                if (ct < 25) {
                    const size_t fo = ((size_t)(ct * 4 + kt) * 64 + l) * 8;
                    const bf16x8 bh = *reinterpret_cast<const bf16x8*>(Bhi + fo);
                    const bf16x8 bl = *reinterpret_cast<const bf16x8*>(Blo + fo);
                    #pragma unroll
                    for (int rt = 0; rt < 4; ++rt) {
                        acc[cti][rt] = __builtin_amdgcn_mfma_f32_16x16x32_bf16(
                            afr[rt], bh, acc[cti][rt], 0, 0, 0);
                        acc[cti][rt] = __builtin_amdgcn_mfma_f32_16x16x32_bf16(
                            afr[rt], bl, acc[cti][rt], 0, 0, 0);
                    }
                }
            }
        }

        // gates (per-wave transpose scratch, k_mid-proven pattern)
        float hval[4][4];
        #pragma unroll
        for (int cti = 0; cti < 4; ++cti) {
            const int ct = w + 8 * cti;
            if (ct < 25) {
                #pragma unroll
                for (int rt = 0; rt < 4; ++rt) {
                    #pragma unroll
                    for (int rr = 0; rr < 4; ++rr)
                        scr[w][(l >> 4) * 4 + rr][l & 15] = acc[cti][rt][rr];
                    const float g0 = scr[w][l >> 2][(l & 3) * 4 + 0];
                    const float g1 = scr[w][l >> 2][(l & 3) * 4 + 1];
                    const float g2 = scr[w][l >> 2][(l & 3) * 4 + 2];
                    const float g3 = scr[w][l >> 2][(l & 3) * 4 + 3];
                    const float ig = sig_(g0);
                    const float fg = sig_(g1);
                    const float gg = tanh_(g2);
                    const float og = sig_(g3);
                    const float cn = fmaf(fg, cst[cti][rt], ig * gg);
                    cst[cti][rt] = cn;
                    hval[cti][rt] = og * tanh_(cn);
                }
            }
        }
        __syncthreads();           // all waves done reading At for step t

        // publish h into A cols 10-109; write Hout [t][u][b]; stage x[t+1]
        #pragma unroll
        for (int cti = 0; cti < 4; ++cti) {
            const int ct = w + 8 * cti;
            if (ct < 25) {
                #pragma unroll
                for (int rt = 0; rt < 4; ++rt) {
                    const __hip_bfloat16 hb = __float2bfloat16(hval[cti][rt]);
                    At[rt * 16 + (l >> 2)][10 + ct * 4 + (l & 3)] = hb;
                    Hout[((size_t)tt * 100 + ct * 4 + (l & 3)) * BTOT
                         + rb + rt * 16 + (l >> 2)] = hb;
                }
            }
        }
        if (t < 19) {
            const int ttn = dir ? (19 - (t + 1)) : (t + 1);
            if (tid < 320) {
                const float v = x[(size_t)ttn * (BTOT * 5) + (size_t)rb * 5 + tid];
                const int row = tid / 5, cc = tid - row * 5;
                const __hip_bfloat16 hi = __float2bfloat16(v);
                At[row][cc]     = hi;
                At[row][5 + cc] = __float2bfloat16(v - __bfloat162float(hi));
            }
        }
        __syncthreads();
    }
}

// ---------------------------------------------------------------------------
// Kernel 2 (round-11 PROVEN, verbatim): MFMA middle LSTM. grid = 256,
// block = 512 (8 waves), 64 rows. A-tile [64][424] bf16. LDS = 62,976 B.
// ---------------------------------------------------------------------------
__global__ __launch_bounds__(512, 2) void k_mid(
    const float* __restrict__ h0m, const float* __restrict__ c0m,
    const __hip_bfloat16* __restrict__ Bhi, const __hip_bfloat16* __restrict__ Blo,
    const __hip_bfloat16* __restrict__ HF, const __hip_bfloat16* __restrict__ HB,
    __hip_bfloat16* __restrict__ HM)
{
    __shared__ __hip_bfloat16 At[64][424];
    __shared__ float scr[8][16][17];

    const int tid = threadIdx.x;
    const int l   = tid & 63;
    const int w   = tid >> 6;
    const int rb  = blockIdx.x * 64;

    float cst[7][4], hval[7][4];
    #pragma unroll
    for (int cti = 0; cti < 7; ++cti) {
        const int ct = w + 8 * cti;
        if (ct < 50) {
            #pragma unroll
            for (int rt = 0; rt < 4; ++rt) {
                const int row = rb + rt * 16 + (l >> 2);
                cst[cti][rt] = c0m[(size_t)row * 200 + ct * 4 + (l & 3)];
            }
        }
    }

    for (int i = tid; i < 12800; i += 512) {
        const int u = i % 200, rr = i / 200;
        At[rr][200 + u] = __float2bfloat16(h0m[(size_t)(rb + rr) * 200 + u]);
    }
    for (int i = tid; i < 1024; i += 512) {
        const int rr = i >> 4, cc = i & 15;
        At[rr][400 + cc] = __float2bfloat16((cc == 15) ? 1.0f : 0.0f);
    }
    for (int i = tid; i < 6400; i += 512) {
        const int rr = i & 63, u = i >> 6;
        At[rr][u]       = HF[(size_t)u * BTOT + rb + rr];
        At[rr][100 + u] = HB[(size_t)u * BTOT + rb + rr];
    }
    __syncthreads();

    for (int t = 0; t < 20; ++t) {
        #pragma unroll
        for (int cti = 0; cti < 7; ++cti) {
            const int ct = w + 8 * cti;
            if (ct < 50) {
                f32x4 acc[4];
                #pragma unroll
                for (int rt = 0; rt < 4; ++rt) acc[rt] = (f32x4){0.f, 0.f, 0.f, 0.f};
                const __hip_bfloat16* bph = Bhi + ((size_t)ct * 13 * 64 + l) * 8;
                const __hip_bfloat16* bpl = Blo + ((size_t)ct * 13 * 64 + l) * 8;
                const int arow = l & 15;
                const int koff = (l >> 4) * 8;
                #pragma unroll
                for (int kt = 0; kt < 13; ++kt) {
                    const bf16x8 bh = *reinterpret_cast<const bf16x8*>(bph + kt * 512);
                    const bf16x8 bl = *reinterpret_cast<const bf16x8*>(bpl + kt * 512);
                    const int ko = kt * 32 + koff;
                    #pragma unroll
                    for (int rt = 0; rt < 4; ++rt) {
                        const bf16x8 a = *reinterpret_cast<const bf16x8*>(&At[rt * 16 + arow][ko]);
                        acc[rt] = __builtin_amdgcn_mfma_f32_16x16x32_bf16(a, bh, acc[rt], 0, 0, 0);
                        acc[rt] = __builtin_amdgcn_mfma_f32_16x16x32_bf16(a, bl, acc[rt], 0, 0, 0);
                    }
                }
                #pragma unroll
                for (int rt = 0; rt < 4; ++rt) {
                    #pragma unroll
                    for (int rr = 0; rr < 4; ++rr)
                        scr[w][(l >> 4) * 4 + rr][l & 15] = acc[rt][rr];
                    const float g0 = scr[w][l >> 2][(l & 3) * 4 + 0];
                    const float g1 = scr[w][l >> 2][(l & 3) * 4 + 1];
                    const float g2 = scr[w][l >> 2][(l & 3) * 4 + 2];
                    const float g3 = scr[w][l >> 2][(l & 3) * 4 + 3];
                    const float ig = sig_(g0);
                    const float fg = sig_(g1);
                    const float gg = tanh_(g2);
                    const float og = sig_(g3);
                    const float cn = fmaf(fg, cst[cti][rt], ig * gg);
                    cst[cti][rt] = cn;
                    hval[cti][rt] = og * tanh_(cn);
                }
            }
        }
        __syncthreads();

        #pragma unroll
        for (int cti = 0; cti < 7; ++cti) {
            const int ct = w + 8 * cti;
            if (ct < 50) {
                #pragma unroll
                for (int rt = 0; rt < 4; ++rt)
                    At[rt * 16 + (l >> 2)][200 + ct * 4 + (l & 3)] =
                        __float2bfloat16(hval[cti][rt]);
            }
        }
        if (t < 19) {
            const __hip_bfloat16* HFt = HF + (size_t)(t + 1) * 100 * BTOT + rb;
            const __hip_bfloat16* HBt = HB + (size_t)(t + 1) * 100 * BTOT + rb;
            for (int i = tid; i < 6400; i += 512) {
                const int rr = i & 63, u = i >> 6;
                At[rr][u]       = HFt[(size_t)u * BTOT + rr];
                At[rr][100 + u] = HBt[(size_t)u * BTOT + rr];
            }
        }
        __syncthreads();
    }

    for (int i = tid; i < 12800; i += 512) {
        const int u = i % 200, rr = i / 200;
        HM[(size_t)(rb + rr) * 200 + u] = At[rr][200 + u];
    }
}

// ---------------------------------------------------------------------------
// Kernel 3 (PROVEN): dense + convT chain, zero-padded LDS tiles.
// ---------------------------------------------------------------------------
__global__ __launch_bounds__(256, 2) void k_head(
    const __hip_bfloat16* __restrict__ HM,
    const float* __restrict__ Wd, const float* __restrict__ bd,
    const float* __restrict__ w1, const float* __restrict__ b1,
    const float* __restrict__ w2, const float* __restrict__ b2,
    const float* __restrict__ w3, const float* __restrict__ b3,
    const float* __restrict__ g1, const float* __restrict__ be1,
    const float* __restrict__ m1, const float* __restrict__ v1,
    const float* __restrict__ g2, const float* __restrict__ be2,
    const float* __restrict__ m2, const float* __restrict__ v2,
    float* __restrict__ out)
{
    __shared__ float hm_s[200];
    __shared__ float y27p[29];
    __shared__ float t1p[128][58];
    __shared__ float t2p[64][110];
    __shared__ float sc1[128], sh1[128], sc2[64], sh2[64];

    const int tid = threadIdx.x;
    const int b   = blockIdx.x;

    if (tid < 200) hm_s[tid] = __bfloat162float(HM[(size_t)b * 200 + tid]);
    if (tid < 128) {
        const float s = g1[tid] * __frsqrt_rn(v1[tid] + 1e-5f);
        sc1[tid] = s; sh1[tid] = be1[tid] - m1[tid] * s;
    } else if (tid < 192) {
        const int cc = tid - 128;
        const float s = g2[cc] * __frsqrt_rn(v2[cc] + 1e-5f);
        sc2[cc] = s; sh2[cc] = be2[cc] - m2[cc] * s;
    }
    {
        const int co = tid >> 1;
        t1p[co][(tid & 1) ? 55 : 0] = 0.0f;
        if (tid < 128) { t1p[tid][56] = 0.0f; t1p[tid][57] = 0.0f; }
        if (tid < 64)  { t2p[tid][0] = 0.0f; t2p[tid][109] = 0.0f; }
        if (tid == 0)  { y27p[0] = 0.0f; y27p[28] = 0.0f; }
    }
    __syncthreads();

    if (tid < 27) {
        float a = bd[tid];
        const float* wr = Wd + tid * 200;
        for (int i = 0; i < 200; ++i) a = fmaf(hm_s[i], wr[i], a);
        y27p[tid + 1] = a;
    }
    __syncthreads();

    for (int idx = tid; idx < 128 * 54; idx += 256) {
        const int co = idx / 54;
        const int ll = idx - co * 54;
        const int q  = (ll + 1) >> 1;
        const float4 w = *reinterpret_cast<const float4*>(w1 + co * 4);
        const float wHI = (ll & 1) ? w.x : w.y;
        const float wLO = (ll & 1) ? w.z : w.w;
        float a = b1[co];
        a = fmaf(y27p[q + 1], wHI, a);
        a = fmaf(y27p[q],     wLO, a);
        a = fmaf(a, sc1[co], sh1[co]);
        t1p[co][ll + 1] = fmaxf(a, 0.0f);
    }
    __syncthreads();

    {
        const int co   = tid & 63;
        const int lseg = tid >> 6;
        const int l0   = lseg * 28;
        const int qb   = lseg * 14;
        float acc[28];
        const float bb = b2[co];
        #pragma unroll
        for (int j = 0; j < 28; ++j) acc[j] = bb;

        #pragma unroll 2
        for (int ci = 0; ci < 128; ++ci) {
            float tv[16];
            #pragma unroll
            for (int j = 0; j < 16; ++j) tv[j] = t1p[ci][qb + j];
            const float4 w = *reinterpret_cast<const float4*>(
                w2 + ((size_t)((ci << 6) + co) << 2));
            #pragma unroll
            for (int j = 0; j < 28; ++j) {
                const int qi = (j + 1) >> 1;
                const float wHI = (j & 1) ? w.x : w.y;
                const float wLO = (j & 1) ? w.z : w.w;
                acc[j] = fmaf(tv[qi + 1], wHI, acc[j]);
                acc[j] = fmaf(tv[qi],     wLO, acc[j]);
            }
        }
        const float s2 = sc2[co], h2 = sh2[co];
        #pragma unroll
        for (int j = 0; j < 28; ++j) {
            const int ll = l0 + j;
            if (ll < 108) t2p[co][ll + 1] = fmaxf(fmaf(acc[j], s2, h2), 0.0f);
        }
    }
    __syncthreads();

    if (tid < 216) {
        const int ll = tid;
        const int q = (ll + 1) >> 1;
        const bool odd = (ll & 1) != 0;
        float a = b3[0];
        #pragma unroll 4
        for (int ci = 0; ci < 64; ++ci) {
            const float4 w = *reinterpret_cast<const float4*>(w3 + ci * 4);
            const float wHI = odd ? w.x : w.y;
            const float wLO = odd ? w.z : w.w;
            a = fmaf(t2p[ci][q + 1], wHI, a);
            a = fmaf(t2p[ci][q],     wLO, a);
        }
        out[(size_t)b * 216 + ll] = a;
    }
}

// ---------------------------------------------------------------------------
extern "C" void kernel_launch(void* const* d_in, const int* in_sizes, int n_in,
                              void* d_out, int out_size, void* d_ws, size_t ws_size,
                              hipStream_t stream) {
    const float* x     = (const float*)d_in[0];
    const float* h0f   = (const float*)d_in[1];
    const float* c0f   = (const float*)d_in[2];
    const float* h0b   = (const float*)d_in[3];
    const float* c0b   = (const float*)d_in[4];
    const float* h0m   = (const float*)d_in[5];
    const float* c0m   = (const float*)d_in[6];
    const float* Wih_f = (const float*)d_in[7];
    const float* Whh_f = (const float*)d_in[8];
    const float* bih_f = (const float*)d_in[9];
    const float* bhh_f = (const float*)d_in[10];
    const float* Wih_b = (const float*)d_in[11];
    const float* Whh_b = (const float*)d_in[12];
    const float* bih_b = (const float*)d_in[13];
    const float* bhh_b = (const float*)d_in[14];
    const float* Wih_m = (const float*)d_in[15];
    const float* Whh_m = (const float*)d_in[16];
    const float* bih_m = (const float*)d_in[17];
    const float* bhh_m = (const float*)d_in[18];
    const float* Wd    = (const float*)d_in[19];
    const float* bd    = (const float*)d_in[20];
    const float* w1    = (const float*)d_in[21];
    const float* b1    = (const float*)d_in[22];
    const float* w2    = (const float*)d_in[23];
    const float* b2    = (const float*)d_in[24];
    const float* w3    = (const float*)d_in[25];
    const float* b3    = (const float*)d_in[26];
    const float* g1    = (const float*)d_in[27];
    const float* be1   = (const float*)d_in[28];
    const float* m1    = (const float*)d_in[29];
    const float* v1    = (const float*)d_in[30];
    const float* g2    = (const float*)d_in[31];
    const float* be2   = (const float*)d_in[32];
    const float* m2    = (const float*)d_in[33];
    const float* v2    = (const float*)d_in[34];

    // ws layout (bytes), total 139,366,400 <= proven 144,179,200:
    //   HF bf16 [20][100][16384]  @ 0            (65,536,000)
    //   HB bf16 [20][100][16384]  @ 65,536,000   (65,536,000)
    //   Bhi_m bf16 [332800]       @ 131,072,000  (665,600)
    //   Blo_m bf16 [332800]       @ 131,737,600  (665,600)
    //   BFhi bf16 [51200]         @ 132,403,200  (102,400)
    //   BFlo bf16 [51200]         @ 132,505,600  (102,400)
    //   BBhi bf16 [51200]         @ 132,608,000  (102,400)
    //   BBlo bf16 [51200]         @ 132,710,400  (102,400)
    //   HM bf16 [16384][200]      @ 132,812,800  (6,553,600)
    char* ws = (char*)d_ws;
    __hip_bfloat16* HF   = (__hip_bfloat16*)ws;
    __hip_bfloat16* HB   = (__hip_bfloat16*)(ws + 65536000);
    __hip_bfloat16* BhiM = (__hip_bfloat16*)(ws + 131072000);
    __hip_bfloat16* BloM = (__hip_bfloat16*)(ws + 131737600);
    __hip_bfloat16* BFhi = (__hip_bfloat16*)(ws + 132403200);
    __hip_bfloat16* BFlo = (__hip_bfloat16*)(ws + 132505600);
    __hip_bfloat16* BBhi = (__hip_bfloat16*)(ws + 132608000);
    __hip_bfloat16* BBlo = (__hip_bfloat16*)(ws + 132710400);
    __hip_bfloat16* HM   = (__hip_bfloat16*)(ws + 132812800);

    k_prep_mfma<<<(332800 + 255) / 256, 256, 0, stream>>>(
        Wih_m, Whh_m, bih_m, bhh_m, BhiM, BloM);
    k_prep_mfma100<<<(51200 + 255) / 256, 256, 0, stream>>>(
        Wih_f, Whh_f, bih_f, bhh_f, BFhi, BFlo);
    k_prep_mfma100<<<(51200 + 255) / 256, 256, 0, stream>>>(
        Wih_b, Whh_b, bih_b, bhh_b, BBhi, BBlo);

    k_lstm100<<<dim3(256, 2), 512, 0, stream>>>(
        x, h0f, c0f, h0b, c0b,
        BFhi, BFlo, BBhi, BBlo, HF, HB);

    k_mid<<<256, 512, 0, stream>>>(
        h0m, c0m, BhiM, BloM, HF, HB, HM);

    k_head<<<16384, 256, 0, stream>>>(
        HM, Wd, bd, w1, b1, w2, b2, w3, b3,
        g1, be1, m1, v1, g2, be2, m2, v2, (float*)d_out);
}